// Round 9
// baseline (918.208 us; speedup 1.0000x reference)
//
#include <hip/hip_runtime.h>
#include <hip/hip_bf16.h>
#include <math.h>

#define N_NODES 40000
#define N_EDGES 400000
#define GCLIP 511

using short8  = __attribute__((ext_vector_type(8))) short;
using ushort8 = __attribute__((ext_vector_type(8))) unsigned short;
using floatx4 = __attribute__((ext_vector_type(4))) float;

__device__ __forceinline__ void split_bf16(float v, unsigned short& hi, unsigned short& lo) {
    __hip_bfloat16 h = __float2bfloat16(v);
    float r = v - __bfloat162float(h);
    __hip_bfloat16 l = __float2bfloat16(r);
    hi = *(unsigned short*)&h;
    lo = *(unsigned short*)&l;
}
__device__ __forceinline__ unsigned short f2bf(float f) {
    __hip_bfloat16 h = __float2bfloat16(f);
    return *(unsigned short*)&h;
}
__device__ __forceinline__ float bf2f(unsigned short u) {
    __hip_bfloat16 h = *(__hip_bfloat16*)&u;
    return __bfloat162float(h);
}
__device__ __forceinline__ floatx4 mfma16(short8 a, short8 b, floatx4 c) {
    return __builtin_amdgcn_mfma_f32_16x16x32_bf16(a, b, c, 0, 0, 0);
}

// ---------------- CSR build ----------------
__global__ void count_kernel(const int* __restrict__ dst, int* __restrict__ cnt, int E) {
    int e = blockIdx.x * 256 + threadIdx.x;
    if (e < E) atomicAdd(&cnt[dst[e]], 1);
}

__global__ void scan1_kernel(const int* __restrict__ cnt, int* __restrict__ rowp,
                             int* __restrict__ bsum, int n) {
    __shared__ int wsum[16];
    __shared__ int woff[16];
    int tid = threadIdx.x, wave = tid >> 6, lane = tid & 63;
    int i = blockIdx.x * 1024 + tid;
    int v = (i < n) ? cnt[i] : 0;
    int x = v;
    for (int off = 1; off < 64; off <<= 1) {
        int t = __shfl_up(x, off);
        if (lane >= off) x += t;
    }
    if (lane == 63) wsum[wave] = x;
    __syncthreads();
    if (wave == 0 && lane < 16) {
        int s = wsum[lane];
        for (int off = 1; off < 16; off <<= 1) {
            int t = __shfl_up(s, off);
            if (lane >= off) s += t;
        }
        woff[lane] = s;
    }
    __syncthreads();
    int incl = x + ((wave == 0) ? 0 : woff[wave - 1]);
    if (i < n) rowp[i] = incl - v;
    if (tid == 1023) bsum[blockIdx.x] = incl;
}

__global__ void scan2_kernel(const int* __restrict__ bsum, int* __restrict__ boffs,
                             int* __restrict__ rowp, int nb, int n) {
    int lane = threadIdx.x;
    int v = (lane < nb) ? bsum[lane] : 0;
    int x = v;
    for (int off = 1; off < 64; off <<= 1) {
        int t = __shfl_up(x, off);
        if (lane >= off) x += t;
    }
    if (lane < nb) boffs[lane] = x - v;
    if (lane == nb - 1) rowp[n] = x;
}

__global__ void scan3_kernel(int* __restrict__ rowp, int* __restrict__ curs,
                             const int* __restrict__ boffs, int n) {
    int i = blockIdx.x * 1024 + threadIdx.x;
    if (i < n) {
        int v = rowp[i] + boffs[blockIdx.x];
        rowp[i] = v;
        curs[i] = v;
    }
}

__global__ void scatter_kernel(const int* __restrict__ src, const int* __restrict__ dst,
                               int* __restrict__ cursor, int2* __restrict__ csr2, int E) {
    int e = blockIdx.x * 256 + threadIdx.x;
    if (e < E) {
        int pos = atomicAdd(&cursor[dst[e]], 1);
        csr2[pos] = make_int2(src[e], e);
    }
}

// ---------------- feature build -> bf16 hi/lo planes [N][32] (cols 16..31 zero) -------
__global__ void feat_kernel(const float* __restrict__ x, const int* __restrict__ batch,
                            const int* __restrict__ gptr, const int* __restrict__ tgid,
                            const float* __restrict__ gp, const float* __restrict__ sp,
                            const float* __restrict__ ep,
                            unsigned short* __restrict__ fhi, unsigned short* __restrict__ flo,
                            int n) {
    int idx = blockIdx.x * 256 + threadIdx.x;
    if (idx >= n * 32) return;
    int node = idx >> 5, c = idx & 31;
    float v = 0.f;
    if (c < 4) {
        v = x[node * 4 + c];
    } else if (c < 7) {
        int gid = gptr[batch[node]] + tgid[node];
        gid = min(max(gid, 0), GCLIP);
        v = gp[gid * 3 + (c - 4)];
    } else if (c < 10) {
        v = sp[node * 3 + (c - 7)];
    } else if (c < 16) {
        int gid = gptr[batch[node]] + tgid[node];
        gid = min(max(gid, 0), GCLIP);
        v = ep[gid * 6 + (c - 10)];
    }
    unsigned short hi, lo;
    split_bf16(v, hi, lo);
    fhi[idx] = hi;
    flo[idx] = lo;
}

// ---------------- weight prep: transpose to [Nrows][Ka] bf16 (hi only) ----------------
#define WOFF_WIN 0
#define WOFF_QKV 6144
#define WOFF_WO  337920
#define WOFF_WF1 448512
#define WOFF_WF2 669696
#define WOFF_HSD 890880
#define WOFF_WE2 964608
#define WTOT     983040

__global__ void prep_kernel(const float* __restrict__ W_in, const float* __restrict__ Wq,
                            const float* __restrict__ Wk, const float* __restrict__ Wv,
                            const float* __restrict__ Wo, const float* __restrict__ Wf1,
                            const float* __restrict__ Wf2, const float* __restrict__ We1,
                            const float* __restrict__ We2, unsigned short* __restrict__ wb) {
    int idx = blockIdx.x * 256 + threadIdx.x;
    if (idx >= WTOT) return;
    float val;
    if (idx < WOFF_QKV) {                       // W_in^T [192][32], K=16 padded
        int n = idx / 32, k = idx % 32;
        val = (k < 16) ? W_in[k * 192 + n] : 0.f;
    } else if (idx < WOFF_WO) {                 // Wqkv^T [576][192] x3; q rows pre-scaled
        int r = idx - WOFF_QKV; int l = r / 110592; r %= 110592;
        int n = r / 192, k = r % 192;
        const float* s = (n < 192) ? Wq : (n < 384 ? Wk : Wv);
        val = s[l * 36864 + k * 192 + (n % 192)];
        if (n < 192) val *= 0.14433756729740643f;   // 1/sqrt(48) folded into Wq
    } else if (idx < WOFF_WF1) {                // Wo^T [192][192] x3
        int r = idx - WOFF_WO; int l = r / 36864; r %= 36864;
        int n = r / 192, k = r % 192;
        val = Wo[l * 36864 + k * 192 + n];
    } else if (idx < WOFF_WF2) {                // Wf1^T [384][192] x3
        int r = idx - WOFF_WF1; int l = r / 73728; r %= 73728;
        int n = r / 192, k = r % 192;
        val = Wf1[l * 73728 + k * 384 + n];
    } else if (idx < WOFF_HSD) {                // Wf2^T [192][384] x3
        int r = idx - WOFF_WF2; int l = r / 73728; r %= 73728;
        int n = r / 384, k = r % 384;
        val = Wf2[l * 73728 + k * 192 + n];
    } else if (idx < WOFF_WE2) {                // [Hs|Hd]^T [384][192]
        int r = idx - WOFF_HSD;
        int n = r / 192, k = r % 192;
        val = (n < 192) ? We1[k * 192 + n] : We1[(192 + k) * 192 + (n - 192)];
    } else {                                    // We2^T [96][192]
        int r = idx - WOFF_WE2;
        int n = r / 192, k = r % 192;
        val = We2[k * 96 + n];
    }
    wb[idx] = f2bf(val);
}

// LDS tile layout: row n holds k-block j (8 ushorts) at slot (j ^ (n&7)); row stride
// SBLK % 8 == 0 blocks -> stride 0 mod 32 dwords -> conflict-free fragment reads.

// ---------------- chunked MFMA GEMM (input proj / wo / ff2) ---------------------------
template <int EPI, int DUAL, int BN, int KCH, int TERMS>
__global__ __launch_bounds__(256, 2)
void mfma_gemm(const unsigned short* __restrict__ Ahi, const unsigned short* __restrict__ Alo,
               int M, int Ka,
               const unsigned short* __restrict__ B, const float* __restrict__ bias,
               const unsigned short* __restrict__ Rhi, const unsigned short* __restrict__ Rlo,
               const float* __restrict__ lng, const float* __restrict__ lnb,
               unsigned short* __restrict__ Chi, unsigned short* __restrict__ Clo, int ldc) {
    constexpr int NT = BN / 16;
    constexpr int JB = KCH / 8;
    constexpr int SBLK = ((JB + 7) / 8) * 8;
    __shared__ __align__(16) unsigned short sB[BN * SBLK * 8];
    const int tid = threadIdx.x;
    const int wave = tid >> 6, lane = tid & 63;
    const int quad = lane >> 4, l16 = lane & 15;
    const int rbase = blockIdx.x * 128;
    const int cbase = blockIdx.y * BN;

    floatx4 acc[2][NT];
#pragma unroll
    for (int mt = 0; mt < 2; ++mt)
#pragma unroll
        for (int nt = 0; nt < NT; ++nt) acc[mt][nt] = (floatx4)0.0f;

    const int r0 = min(rbase + wave * 32 + l16, M - 1);
    const int r1 = min(rbase + wave * 32 + 16 + l16, M - 1);
    const unsigned short* pa0h = Ahi + (size_t)r0 * Ka + quad * 8;
    const unsigned short* pa1h = Ahi + (size_t)r1 * Ka + quad * 8;
    const unsigned short* pa0l = Alo + (size_t)r0 * Ka + quad * 8;
    const unsigned short* pa1l = Alo + (size_t)r1 * Ka + quad * 8;

    for (int kb = 0; kb < Ka; kb += KCH) {
        if (kb) __syncthreads();
        for (int i = tid; i < BN * JB; i += 256) {
            int n = i % BN, j = i / BN;
            *(uint4*)&sB[(n * SBLK + (j ^ (n & 7))) * 8] =
                *(const uint4*)(B + (size_t)(cbase + n) * Ka + kb + j * 8);
        }
        __syncthreads();
        short8 ch0 = *(const short8*)(pa0h + kb);
        short8 ch1 = *(const short8*)(pa1h + kb);
        short8 cl0, cl1;
        if (TERMS == 2) {
            cl0 = *(const short8*)(pa0l + kb);
            cl1 = *(const short8*)(pa1l + kb);
        }
#pragma unroll
        for (int kc = 0; kc < KCH; kc += 32) {
            short8 nh0 = ch0, nh1 = ch1, nl0 = ch0, nl1 = ch1;
            if (kc + 32 < KCH) {
                nh0 = *(const short8*)(pa0h + kb + kc + 32);
                nh1 = *(const short8*)(pa1h + kb + kc + 32);
                if (TERMS == 2) {
                    nl0 = *(const short8*)(pa0l + kb + kc + 32);
                    nl1 = *(const short8*)(pa1l + kb + kc + 32);
                }
            }
            const int jbase = kc / 8;
#pragma unroll
            for (int nt = 0; nt < NT; ++nt) {
                int jj = (jbase + quad) ^ (l16 & 7);
                short8 b = *(const short8*)&sB[((nt * 16 + l16) * SBLK + jj) * 8];
                acc[0][nt] = mfma16(ch0, b, acc[0][nt]);
                if (TERMS == 2) acc[0][nt] = mfma16(cl0, b, acc[0][nt]);
                acc[1][nt] = mfma16(ch1, b, acc[1][nt]);
                if (TERMS == 2) acc[1][nt] = mfma16(cl1, b, acc[1][nt]);
            }
            ch0 = nh0; ch1 = nh1;
            if (TERMS == 2) { cl0 = nl0; cl1 = nl1; }
        }
    }

    float bb[NT], gg[NT], be[NT];
#pragma unroll
    for (int nt = 0; nt < NT; ++nt) {
        int colg = cbase + nt * 16 + l16;
        bb[nt] = bias ? bias[colg] : 0.f;
        if (EPI == 2) { gg[nt] = lng[colg]; be[nt] = lnb[colg]; }
    }
#pragma unroll
    for (int mt = 0; mt < 2; ++mt) {
#pragma unroll
        for (int reg = 0; reg < 4; ++reg) {
            int row = rbase + wave * 32 + mt * 16 + quad * 4 + reg;
            if (EPI == 2) {
                int rr = min(row, M - 1);
                float v[NT], s = 0.f, q = 0.f;
#pragma unroll
                for (int nt = 0; nt < NT; ++nt) {
                    size_t off = (size_t)rr * 192 + nt * 16 + l16;
                    float resid = bf2f(Rhi[off]) + bf2f(Rlo[off]);
                    v[nt] = acc[mt][nt][reg] + bb[nt] + resid;
                    s += v[nt]; q += v[nt] * v[nt];
                }
#pragma unroll
                for (int off = 1; off < 16; off <<= 1) {
                    s += __shfl_xor(s, off);
                    q += __shfl_xor(q, off);
                }
                float mean = s * (1.f / 192.f);
                float var = q * (1.f / 192.f) - mean * mean;
                float rs = rsqrtf(var + 1e-5f);
                if (row < M) {
#pragma unroll
                    for (int nt = 0; nt < NT; ++nt) {
                        float r = (v[nt] - mean) * rs * gg[nt] + be[nt];
                        unsigned short hi, lo;
                        split_bf16(r, hi, lo);
                        size_t off = (size_t)row * 192 + nt * 16 + l16;
                        Chi[off] = hi; Clo[off] = lo;
                    }
                }
            } else if (row < M) {
#pragma unroll
                for (int nt = 0; nt < NT; ++nt) {
                    float v = acc[mt][nt][reg] + bb[nt];
                    if (EPI == 1) v = fmaxf(v, 0.f);
                    size_t off = (size_t)row * ldc + cbase + nt * 16 + l16;
                    if (DUAL) {
                        unsigned short hi, lo;
                        split_bf16(v, hi, lo);
                        Chi[off] = hi; Clo[off] = lo;
                    } else {
                        Chi[off] = f2bf(v);
                    }
                }
            }
        }
    }
}

// ---------------- A-stationary MFMA GEMM (qkv / ff1 / hsd) ----------------------------
template <int EPI, int DUAL, int BN, int NTILES, int TERMS, int KF, int OUTMODE>
__global__ __launch_bounds__(256, 2)
void mfma_gemm_astat(const unsigned short* __restrict__ Ahi, const unsigned short* __restrict__ Alo,
                     int M, const unsigned short* __restrict__ B, const float* __restrict__ bias,
                     unsigned short* __restrict__ Chi, unsigned short* __restrict__ Clo, int ldc) {
    constexpr int NT = BN / 16;
    constexpr int Ka = KF * 32;
    constexpr int SBLK = KF * 4;
    __shared__ __align__(16) unsigned short sB[BN * SBLK * 8];
    const int tid = threadIdx.x;
    const int wave = tid >> 6, lane = tid & 63;
    const int quad = lane >> 4, l16 = lane & 15;
    const int rbase = blockIdx.x * 128;

    const int r0 = min(rbase + wave * 32 + l16, M - 1);
    const int r1 = min(rbase + wave * 32 + 16 + l16, M - 1);
    const unsigned short* pa0h = Ahi + (size_t)r0 * Ka + quad * 8;
    const unsigned short* pa1h = Ahi + (size_t)r1 * Ka + quad * 8;
    const unsigned short* pa0l = Alo + (size_t)r0 * Ka + quad * 8;
    const unsigned short* pa1l = Alo + (size_t)r1 * Ka + quad * 8;

    short8 afh[2][KF], afl[2][KF];
#pragma unroll
    for (int kf = 0; kf < KF; ++kf) {
        afh[0][kf] = *(const short8*)(pa0h + kf * 32);
        afh[1][kf] = *(const short8*)(pa1h + kf * 32);
        if (TERMS == 2) {
            afl[0][kf] = *(const short8*)(pa0l + kf * 32);
            afl[1][kf] = *(const short8*)(pa1l + kf * 32);
        }
    }

    for (int t = 0; t < NTILES; ++t) {
        const int cbase = t * BN;
        if (t) __syncthreads();
        for (int i = tid; i < BN * KF * 4; i += 256) {
            int n = i % BN, j = i / BN;
            *(uint4*)&sB[(n * SBLK + (j ^ (n & 7))) * 8] =
                *(const uint4*)(B + (size_t)(cbase + n) * Ka + j * 8);
        }
        __syncthreads();

        floatx4 acc[2][NT];
#pragma unroll
        for (int mt = 0; mt < 2; ++mt)
#pragma unroll
            for (int nt = 0; nt < NT; ++nt) acc[mt][nt] = (floatx4)0.0f;

#pragma unroll
        for (int kf = 0; kf < KF; ++kf) {
#pragma unroll
            for (int nt = 0; nt < NT; ++nt) {
                int jj = (kf * 4 + quad) ^ (l16 & 7);
                short8 b = *(const short8*)&sB[((nt * 16 + l16) * SBLK + jj) * 8];
                acc[0][nt] = mfma16(afh[0][kf], b, acc[0][nt]);
                if (TERMS == 2) acc[0][nt] = mfma16(afl[0][kf], b, acc[0][nt]);
                acc[1][nt] = mfma16(afh[1][kf], b, acc[1][nt]);
                if (TERMS == 2) acc[1][nt] = mfma16(afl[1][kf], b, acc[1][nt]);
            }
        }

        float bb[NT];
#pragma unroll
        for (int nt = 0; nt < NT; ++nt) bb[nt] = bias ? bias[cbase + nt * 16 + l16] : 0.f;
#pragma unroll
        for (int mt = 0; mt < 2; ++mt) {
#pragma unroll
            for (int reg = 0; reg < 4; ++reg) {
                int row = rbase + wave * 32 + mt * 16 + quad * 4 + reg;
                if (row < M) {
#pragma unroll
                    for (int nt = 0; nt < NT; ++nt) {
                        float v = acc[mt][nt][reg] + bb[nt];
                        if (EPI == 1) v = fmaxf(v, 0.f);
                        if (OUTMODE == 1) {
                            int c = cbase + nt * 16 + l16;
                            if (c < 192) {
                                Chi[(size_t)row * 192 + c] = f2bf(v);
                            } else {
                                int cc = c - 192;
                                int idx = (cc < 192) ? (cc * 2) : ((cc - 192) * 2 + 1);
                                Clo[(size_t)row * 384 + idx] = f2bf(v);
                            }
                        } else {
                            size_t off = (size_t)row * ldc + cbase + nt * 16 + l16;
                            if (DUAL) {
                                unsigned short hi, lo;
                                split_bf16(v, hi, lo);
                                Chi[off] = hi; Clo[off] = lo;
                            } else {
                                Chi[off] = f2bf(v);
                            }
                        }
                    }
                }
            }
        }
    }
}

// ---------------- edge attention (round-6 layout, msgH-only output) -------------------
// no-max softmax (exact, shift-invariant; logits O(3)); 4-edge unroll.
__global__ __launch_bounds__(256)
void attn_kernel(const unsigned short* __restrict__ qB, const unsigned short* __restrict__ kvB,
                 const float* __restrict__ ea, const float* __restrict__ We_l,
                 const int2* __restrict__ csr2, const int* __restrict__ row_ptr,
                 unsigned short* __restrict__ msg_hi) {
    __shared__ float sWe[768];
    const int tid = threadIdx.x;
    for (int i = tid; i < 768; i += 256) sWe[i] = We_l[i];
    __syncthreads();

    const int lane = tid & 63;
    const int node = blockIdx.x * 4 + (tid >> 6);
    const int d0 = (lane >> 4) * 48 + (lane & 15) * 3;

    float W[4][3];
#pragma unroll
    for (int w = 0; w < 4; ++w) {
        W[w][0] = sWe[w * 192 + d0];
        W[w][1] = sWe[w * 192 + d0 + 1];
        W[w][2] = sWe[w * 192 + d0 + 2];
    }
    size_t qoff = (size_t)node * 192 + d0;
    float q0 = bf2f(qB[qoff]), q1 = bf2f(qB[qoff + 1]), q2 = bf2f(qB[qoff + 2]);
    float qe0 = q0 * W[0][0] + q1 * W[0][1] + q2 * W[0][2];
    float qe1 = q0 * W[1][0] + q1 * W[1][1] + q2 * W[1][2];
    float qe2 = q0 * W[2][0] + q1 * W[2][1] + q2 * W[2][2];
    float qe3 = q0 * W[3][0] + q1 * W[3][1] + q2 * W[3][2];
#pragma unroll
    for (int off = 1; off < 16; off <<= 1) {
        qe0 += __shfl_xor(qe0, off);
        qe1 += __shfl_xor(qe1, off);
        qe2 += __shfl_xor(qe2, off);
        qe3 += __shfl_xor(qe3, off);
    }

    const unsigned int* kv = (const unsigned int*)kvB;
    const float4* ea4 = (const float4*)ea;

    float den = 0.f;
    float v0 = 0.f, v1 = 0.f, v2 = 0.f;
    float wa0 = 0.f, wa1 = 0.f, wa2 = 0.f, wa3 = 0.f;
    const int beg = row_ptr[node], end = row_ptr[node + 1];
    int p = beg;
    for (; p + 3 < end; p += 4) {
        int2 seA = csr2[p], seB = csr2[p + 1], seC = csr2[p + 2], seD = csr2[p + 3];
        size_t bA = (size_t)seA.x * 192 + d0;
        size_t bB = (size_t)seB.x * 192 + d0;
        size_t bC = (size_t)seC.x * 192 + d0;
        size_t bD = (size_t)seD.x * 192 + d0;
        unsigned int uA0 = kv[bA], uA1 = kv[bA + 1], uA2 = kv[bA + 2];
        unsigned int uB0 = kv[bB], uB1 = kv[bB + 1], uB2 = kv[bB + 2];
        unsigned int uC0 = kv[bC], uC1 = kv[bC + 1], uC2 = kv[bC + 2];
        unsigned int uD0 = kv[bD], uD1 = kv[bD + 1], uD2 = kv[bD + 2];
        float4 wA = ea4[seA.y], wB = ea4[seB.y], wC = ea4[seC.y], wD = ea4[seD.y];
        float dA = q0 * bf2f((unsigned short)uA0) + q1 * bf2f((unsigned short)uA1) + q2 * bf2f((unsigned short)uA2);
        float dB = q0 * bf2f((unsigned short)uB0) + q1 * bf2f((unsigned short)uB1) + q2 * bf2f((unsigned short)uB2);
        float dC = q0 * bf2f((unsigned short)uC0) + q1 * bf2f((unsigned short)uC1) + q2 * bf2f((unsigned short)uC2);
        float dD = q0 * bf2f((unsigned short)uD0) + q1 * bf2f((unsigned short)uD1) + q2 * bf2f((unsigned short)uD2);
#pragma unroll
        for (int off = 1; off < 16; off <<= 1) {
            dA += __shfl_xor(dA, off);
            dB += __shfl_xor(dB, off);
            dC += __shfl_xor(dC, off);
            dD += __shfl_xor(dD, off);
        }
        float pA = __expf(dA + wA.x * qe0 + wA.y * qe1 + wA.z * qe2 + wA.w * qe3);
        float pB = __expf(dB + wB.x * qe0 + wB.y * qe1 + wB.z * qe2 + wB.w * qe3);
        float pC = __expf(dC + wC.x * qe0 + wC.y * qe1 + wC.z * qe2 + wC.w * qe3);
        float pD = __expf(dD + wD.x * qe0 + wD.y * qe1 + wD.z * qe2 + wD.w * qe3);
        den += pA + pB + pC + pD;
        v0 += pA * bf2f((unsigned short)(uA0 >> 16)) + pB * bf2f((unsigned short)(uB0 >> 16))
            + pC * bf2f((unsigned short)(uC0 >> 16)) + pD * bf2f((unsigned short)(uD0 >> 16));
        v1 += pA * bf2f((unsigned short)(uA1 >> 16)) + pB * bf2f((unsigned short)(uB1 >> 16))
            + pC * bf2f((unsigned short)(uC1 >> 16)) + pD * bf2f((unsigned short)(uD1 >> 16));
        v2 += pA * bf2f((unsigned short)(uA2 >> 16)) + pB * bf2f((unsigned short)(uB2 >> 16))
            + pC * bf2f((unsigned short)(uC2 >> 16)) + pD * bf2f((unsigned short)(uD2 >> 16));
        wa0 += pA * wA.x + pB * wB.x + pC * wC.x + pD * wD.x;
        wa1 += pA * wA.y + pB * wB.y + pC * wC.y + pD * wD.y;
        wa2 += pA * wA.z + pB * wB.z + pC * wC.z + pD * wD.z;
        wa3 += pA * wA.w + pB * wB.w + pC * wC.w + pD * wD.w;
    }
    for (; p < end; ++p) {
        int2 se = csr2[p];
        size_t b = (size_t)se.x * 192 + d0;
        unsigned int u0 = kv[b], u1 = kv[b + 1], u2 = kv[b + 2];
        float4 w = ea4[se.y];
        float d = q0 * bf2f((unsigned short)u0) + q1 * bf2f((unsigned short)u1)
                + q2 * bf2f((unsigned short)u2);
#pragma unroll
        for (int off = 1; off < 16; off <<= 1) d += __shfl_xor(d, off);
        float pe = __expf(d + w.x * qe0 + w.y * qe1 + w.z * qe2 + w.w * qe3);
        den += pe;
        v0 += pe * bf2f((unsigned short)(u0 >> 16));
        v1 += pe * bf2f((unsigned short)(u1 >> 16));
        v2 += pe * bf2f((unsigned short)(u2 >> 16));
        wa0 += pe * w.x;
        wa1 += pe * w.y;
        wa2 += pe * w.z;
        wa3 += pe * w.w;
    }
    float inv = 1.f / (den + 1e-16f);
    float m0 = (v0 + wa0 * W[0][0] + wa1 * W[1][0] + wa2 * W[2][0] + wa3 * W[3][0]) * inv;
    float m1 = (v1 + wa0 * W[0][1] + wa1 * W[1][1] + wa2 * W[2][1] + wa3 * W[3][1]) * inv;
    float m2 = (v2 + wa0 * W[0][2] + wa1 * W[1][2] + wa2 * W[2][2] + wa3 * W[3][2]) * inv;
    size_t ob = (size_t)node * 192 + d0;
    msg_hi[ob]     = f2bf(m0);
    msg_hi[ob + 1] = f2bf(m1);
    msg_hi[ob + 2] = f2bf(m2);
}

// ---------------- edge head: register A-fragments, W2 fragments direct from L1/L2 ----
// (round-7 variant, reintroduced in isolation: LDS 3.8 KB -> high occupancy)
__global__ __launch_bounds__(256)
void edge_head_kernel(const unsigned short* __restrict__ hsd, const float* __restrict__ ea,
                      const int* __restrict__ src, const int* __restrict__ dst,
                      const float* __restrict__ W1e, const float* __restrict__ b1,
                      const unsigned short* __restrict__ W2hi,
                      const float* __restrict__ b2, const float* __restrict__ W3,
                      const float* __restrict__ b3, float* __restrict__ out) {
    __shared__ __align__(16) float sWe1[768];
    __shared__ __align__(16) float sB1[192];
    const int tid = threadIdx.x;
    const int wave = tid >> 6, lane = tid & 63;
    const int quad = lane >> 4, l16 = lane & 15;
    const int ebase = blockIdx.x * 64;

    for (int i = tid; i < 768; i += 256) sWe1[i] = W1e[i];
    if (tid < 192) sB1[tid] = b1[tid];

    const int e = ebase + wave * 16 + l16;        // this lane's edge
    const int s = src[e], d = dst[e];
    const float4 eav = *(const float4*)(ea + (size_t)e * 4);
    const unsigned short* hs_p = hsd + (size_t)s * 384 + quad * 8;
    const unsigned short* hd_p = hsd + (size_t)d * 384 + 192 + quad * 8;

    floatx4 acc[6];
#pragma unroll
    for (int nt = 0; nt < 6; ++nt) acc[nt] = (floatx4)0.0f;
    __syncthreads();

    ushort8 hs_c = *(const ushort8*)hs_p;
    ushort8 hd_c = *(const ushort8*)hd_p;
#pragma unroll
    for (int kc = 0; kc < 192; kc += 32) {
        ushort8 hs_n = hs_c, hd_n = hd_c;
        if (kc + 32 < 192) {
            hs_n = *(const ushort8*)(hs_p + kc + 32);
            hd_n = *(const ushort8*)(hd_p + kc + 32);
        }
        const int c0 = kc + quad * 8;
        float wb1[8], w0v[8], w1v[8], w2v[8], w3v[8];
        *(float4*)&wb1[0] = *(const float4*)&sB1[c0];
        *(float4*)&wb1[4] = *(const float4*)&sB1[c0 + 4];
        *(float4*)&w0v[0] = *(const float4*)&sWe1[c0];
        *(float4*)&w0v[4] = *(const float4*)&sWe1[c0 + 4];
        *(float4*)&w1v[0] = *(const float4*)&sWe1[192 + c0];
        *(float4*)&w1v[4] = *(const float4*)&sWe1[192 + c0 + 4];
        *(float4*)&w2v[0] = *(const float4*)&sWe1[384 + c0];
        *(float4*)&w2v[4] = *(const float4*)&sWe1[384 + c0 + 4];
        *(float4*)&w3v[0] = *(const float4*)&sWe1[576 + c0];
        *(float4*)&w3v[4] = *(const float4*)&sWe1[576 + c0 + 4];
        ushort8 ah;
#pragma unroll
        for (int j = 0; j < 8; ++j) {
            float ce = wb1[j] + eav.x * w0v[j] + eav.y * w1v[j]
                     + eav.z * w2v[j] + eav.w * w3v[j];
            float v = fmaxf(bf2f(hs_c[j]) + bf2f(hd_c[j]) + ce, 0.f);
            ah[j] = f2bf(v);
        }
        short8 ahs = *(short8*)&ah;
#pragma unroll
        for (int nt = 0; nt < 6; ++nt) {
            // B fragment straight from global: W2 is 37 KB, L1/L2-hot, shared by all waves
            short8 bh = *(const short8*)(W2hi + (size_t)(nt * 16 + l16) * 192 + kc + quad * 8);
            acc[nt] = mfma16(ahs, bh, acc[nt]);
        }
        hs_c = hs_n; hd_c = hd_n;
    }

    float w3[6], bb2[6];
#pragma unroll
    for (int nt = 0; nt < 6; ++nt) {
        int col = nt * 16 + l16;
        w3[nt] = W3[col];
        bb2[nt] = b2[col];
    }
    float b3v = b3[0];
#pragma unroll
    for (int reg = 0; reg < 4; ++reg) {
        float sacc = 0.f;
#pragma unroll
        for (int nt = 0; nt < 6; ++nt) {
            float z = fmaxf(acc[nt][reg] + bb2[nt], 0.f);
            sacc = fmaf(z, w3[nt], sacc);
        }
#pragma unroll
        for (int off = 1; off < 16; off <<= 1) sacc += __shfl_xor(sacc, off);
        if (l16 == 0) out[ebase + wave * 16 + quad * 4 + reg] = sacc + b3v;
    }
}

extern "C" void kernel_launch(void* const* d_in, const int* in_sizes, int n_in,
                              void* d_out, int out_size, void* d_ws, size_t ws_size,
                              hipStream_t stream) {
    const float* x     = (const float*)d_in[0];
    const int*   eidx  = (const int*)d_in[1];
    const float* ea    = (const float*)d_in[2];
    const int*   batch = (const int*)d_in[3];
    const int*   gptr  = (const int*)d_in[4];
    const int*   tgid  = (const int*)d_in[5];
    const float* gp    = (const float*)d_in[6];
    const float* sp    = (const float*)d_in[7];
    const float* epp   = (const float*)d_in[8];
    const float* W_in  = (const float*)d_in[9];
    const float* b_in  = (const float*)d_in[10];
    const float* Wq    = (const float*)d_in[11];
    const float* Wk    = (const float*)d_in[12];
    const float* Wv    = (const float*)d_in[13];
    const float* We    = (const float*)d_in[14];
    const float* Wo    = (const float*)d_in[15];
    const float* bo    = (const float*)d_in[16];
    const float* ln1g  = (const float*)d_in[17];
    const float* ln1b  = (const float*)d_in[18];
    const float* Wf1   = (const float*)d_in[19];
    const float* bf1   = (const float*)d_in[20];
    const float* Wf2   = (const float*)d_in[21];
    const float* bf2   = (const float*)d_in[22];
    const float* ln2g  = (const float*)d_in[23];
    const float* ln2b  = (const float*)d_in[24];
    const float* We1   = (const float*)d_in[25];
    const float* be1   = (const float*)d_in[26];
    const float* We2   = (const float*)d_in[27];
    const float* be2   = (const float*)d_in[28];
    const float* We3   = (const float*)d_in[29];
    const float* be3   = (const float*)d_in[30];
    const int* src = eidx;
    const int* dst = eidx + N_EDGES;

    unsigned short* ub = (unsigned short*)d_ws;
    unsigned short* featH = ub;                  // 40000*32
    unsigned short* featL = ub + 1280000;
    unsigned short* hH    = ub + 2560000;        // 40000*192 each
    unsigned short* hL    = ub + 10240000;
    unsigned short* htH   = ub + 17920000;
    unsigned short* htL   = ub + 25600000;
    unsigned short* msgH  = ub + 33280000;
    unsigned short* rbuf  = ub + 48640000;       // 40000*768 region
    unsigned short* qB    = rbuf;                // 40000*192
    unsigned short* kvB   = rbuf + 7680000;      // 40000*384 interleaved k/v
    unsigned short* ffH   = rbuf;                // 40000*384 (after attn)
    unsigned short* hsdB  = rbuf;                // 40000*384
    unsigned short* wb    = ub + 79360000;       // WTOT
    int* ib   = (int*)(ub + 80343040);
    int* cnt  = ib;
    int* rowp = ib + 40000;
    int* curs = ib + 80004;
    int2* csr2 = (int2*)(ib + 120004);
    int* bsum  = ib + 920004;
    int* boffs = ib + 920044;

    hipMemsetAsync(cnt, 0, N_NODES * sizeof(int), stream);
    count_kernel<<<1563, 256, 0, stream>>>(dst, cnt, N_EDGES);
    scan1_kernel<<<40, 1024, 0, stream>>>(cnt, rowp, bsum, N_NODES);
    scan2_kernel<<<1, 64, 0, stream>>>(bsum, boffs, rowp, 40, N_NODES);
    scan3_kernel<<<40, 1024, 0, stream>>>(rowp, curs, boffs, N_NODES);
    scatter_kernel<<<1563, 256, 0, stream>>>(src, dst, curs, csr2, N_EDGES);
    feat_kernel<<<5000, 256, 0, stream>>>(x, batch, gptr, tgid, gp, sp, epp, featH, featL, N_NODES);
    prep_kernel<<<3840, 256, 0, stream>>>(W_in, Wq, Wk, Wv, Wo, Wf1, Wf2, We1, We2, wb);

    dim3 blk(256);
    // input projection: feat[40000, K=32 planes] @ W_in -> h planes (chunked path)
    mfma_gemm<0, 1, 96, 32, 2><<<dim3(313, 2), blk, 0, stream>>>(featH, featL, N_NODES, 32,
        wb + WOFF_WIN, b_in, nullptr, nullptr, nullptr, nullptr, hH, hL, 192);

    for (int l = 0; l < 3; ++l) {
        const unsigned short* wq = wb + WOFF_QKV + l * 110592;
        // fused qkv, A-stationary: q -> qB, k/v -> kvB interleaved (single-term A)
        mfma_gemm_astat<0, 0, 96, 6, 1, 6, 1><<<313, blk, 0, stream>>>(hH, hL, N_NODES,
            wq, nullptr, qB, kvB, 0);
        attn_kernel<<<10000, blk, 0, stream>>>(qB, kvB, ea, We + l * 768, csr2, rowp, msgH);
        // wo + residual + LN (msg single-plane -> TERMS=1); KCH=64 for occupancy
        mfma_gemm<2, 1, 192, 64, 1><<<dim3(313, 1), blk, 0, stream>>>(msgH, msgH, N_NODES, 192,
            wb + WOFF_WO + l * 36864, bo + l * 192, hH, hL, ln1g + l * 192, ln1b + l * 192,
            htH, htL, 192);
        // ff1: relu, single-plane output
        mfma_gemm_astat<1, 0, 96, 4, 2, 6, 0><<<313, blk, 0, stream>>>(htH, htL, N_NODES,
            wb + WOFF_WF1 + l * 73728, bf1 + l * 384, ffH, nullptr, 384);
        // ff2 + residual + LN (ff single-plane -> TERMS=1); KCH=64 for occupancy
        mfma_gemm<2, 1, 192, 64, 1><<<dim3(313, 1), blk, 0, stream>>>(ffH, ffH, N_NODES, 384,
            wb + WOFF_WF2 + l * 73728, bf2 + l * 192, htH, htL, ln2g + l * 192, ln2b + l * 192,
            hH, hL, 192);
    }

    // edge head pre-projections, A-stationary: [Hs|Hd] -> hsdB bf16 [N,384]
    mfma_gemm_astat<0, 0, 96, 4, 2, 6, 0><<<313, blk, 0, stream>>>(hH, hL, N_NODES,
        wb + WOFF_HSD, nullptr, hsdB, nullptr, 384);
    edge_head_kernel<<<6250, blk, 0, stream>>>(hsdB, ea, src, dst,
        We1 + 384 * 192, be1, wb + WOFF_WE2, be2, We3, be3, (float*)d_out);
}

// Round 10
// 855.612 us; speedup vs baseline: 1.0732x; 1.0732x over previous
//
#include <hip/hip_runtime.h>
#include <hip/hip_bf16.h>
#include <math.h>

#define N_NODES 40000
#define N_EDGES 400000
#define GCLIP 511

using short8  = __attribute__((ext_vector_type(8))) short;
using ushort8 = __attribute__((ext_vector_type(8))) unsigned short;
using floatx4 = __attribute__((ext_vector_type(4))) float;

__device__ __forceinline__ void split_bf16(float v, unsigned short& hi, unsigned short& lo) {
    __hip_bfloat16 h = __float2bfloat16(v);
    float r = v - __bfloat162float(h);
    __hip_bfloat16 l = __float2bfloat16(r);
    hi = *(unsigned short*)&h;
    lo = *(unsigned short*)&l;
}
__device__ __forceinline__ unsigned short f2bf(float f) {
    __hip_bfloat16 h = __float2bfloat16(f);
    return *(unsigned short*)&h;
}
__device__ __forceinline__ float bf2f(unsigned short u) {
    __hip_bfloat16 h = *(__hip_bfloat16*)&u;
    return __bfloat162float(h);
}
__device__ __forceinline__ floatx4 mfma16(short8 a, short8 b, floatx4 c) {
    return __builtin_amdgcn_mfma_f32_16x16x32_bf16(a, b, c, 0, 0, 0);
}

// ---------------- CSR build ----------------
__global__ void count_kernel(const int* __restrict__ dst, int* __restrict__ cnt, int E) {
    int e = blockIdx.x * 256 + threadIdx.x;
    if (e < E) atomicAdd(&cnt[dst[e]], 1);
}

__global__ void scan1_kernel(const int* __restrict__ cnt, int* __restrict__ rowp,
                             int* __restrict__ bsum, int n) {
    __shared__ int wsum[16];
    __shared__ int woff[16];
    int tid = threadIdx.x, wave = tid >> 6, lane = tid & 63;
    int i = blockIdx.x * 1024 + tid;
    int v = (i < n) ? cnt[i] : 0;
    int x = v;
    for (int off = 1; off < 64; off <<= 1) {
        int t = __shfl_up(x, off);
        if (lane >= off) x += t;
    }
    if (lane == 63) wsum[wave] = x;
    __syncthreads();
    if (wave == 0 && lane < 16) {
        int s = wsum[lane];
        for (int off = 1; off < 16; off <<= 1) {
            int t = __shfl_up(s, off);
            if (lane >= off) s += t;
        }
        woff[lane] = s;
    }
    __syncthreads();
    int incl = x + ((wave == 0) ? 0 : woff[wave - 1]);
    if (i < n) rowp[i] = incl - v;
    if (tid == 1023) bsum[blockIdx.x] = incl;
}

__global__ void scan2_kernel(const int* __restrict__ bsum, int* __restrict__ boffs,
                             int* __restrict__ rowp, int nb, int n) {
    int lane = threadIdx.x;
    int v = (lane < nb) ? bsum[lane] : 0;
    int x = v;
    for (int off = 1; off < 64; off <<= 1) {
        int t = __shfl_up(x, off);
        if (lane >= off) x += t;
    }
    if (lane < nb) boffs[lane] = x - v;
    if (lane == nb - 1) rowp[n] = x;
}

__global__ void scan3_kernel(int* __restrict__ rowp, int* __restrict__ curs,
                             const int* __restrict__ boffs, int n) {
    int i = blockIdx.x * 1024 + threadIdx.x;
    if (i < n) {
        int v = rowp[i] + boffs[blockIdx.x];
        rowp[i] = v;
        curs[i] = v;
    }
}

__global__ void scatter_kernel(const int* __restrict__ src, const int* __restrict__ dst,
                               int* __restrict__ cursor, int2* __restrict__ csr2, int E) {
    int e = blockIdx.x * 256 + threadIdx.x;
    if (e < E) {
        int pos = atomicAdd(&cursor[dst[e]], 1);
        csr2[pos] = make_int2(src[e], e);
    }
}

// ---------------- feature build -> bf16 hi/lo planes [N][32] (cols 16..31 zero) -------
__global__ void feat_kernel(const float* __restrict__ x, const int* __restrict__ batch,
                            const int* __restrict__ gptr, const int* __restrict__ tgid,
                            const float* __restrict__ gp, const float* __restrict__ sp,
                            const float* __restrict__ ep,
                            unsigned short* __restrict__ fhi, unsigned short* __restrict__ flo,
                            int n) {
    int idx = blockIdx.x * 256 + threadIdx.x;
    if (idx >= n * 32) return;
    int node = idx >> 5, c = idx & 31;
    float v = 0.f;
    if (c < 4) {
        v = x[node * 4 + c];
    } else if (c < 7) {
        int gid = gptr[batch[node]] + tgid[node];
        gid = min(max(gid, 0), GCLIP);
        v = gp[gid * 3 + (c - 4)];
    } else if (c < 10) {
        v = sp[node * 3 + (c - 7)];
    } else if (c < 16) {
        int gid = gptr[batch[node]] + tgid[node];
        gid = min(max(gid, 0), GCLIP);
        v = ep[gid * 6 + (c - 10)];
    }
    unsigned short hi, lo;
    split_bf16(v, hi, lo);
    fhi[idx] = hi;
    flo[idx] = lo;
}

// ---------------- weight prep: transpose to [Nrows][Ka] bf16 (hi only) ----------------
#define WOFF_WIN 0
#define WOFF_QKV 6144
#define WOFF_WO  337920
#define WOFF_WF1 448512
#define WOFF_WF2 669696
#define WOFF_HSD 890880
#define WOFF_WE2 964608
#define WTOT     983040

__global__ void prep_kernel(const float* __restrict__ W_in, const float* __restrict__ Wq,
                            const float* __restrict__ Wk, const float* __restrict__ Wv,
                            const float* __restrict__ Wo, const float* __restrict__ Wf1,
                            const float* __restrict__ Wf2, const float* __restrict__ We1,
                            const float* __restrict__ We2, unsigned short* __restrict__ wb) {
    int idx = blockIdx.x * 256 + threadIdx.x;
    if (idx >= WTOT) return;
    float val;
    if (idx < WOFF_QKV) {                       // W_in^T [192][32], K=16 padded
        int n = idx / 32, k = idx % 32;
        val = (k < 16) ? W_in[k * 192 + n] : 0.f;
    } else if (idx < WOFF_WO) {                 // Wqkv^T [576][192] x3; q rows pre-scaled
        int r = idx - WOFF_QKV; int l = r / 110592; r %= 110592;
        int n = r / 192, k = r % 192;
        const float* s = (n < 192) ? Wq : (n < 384 ? Wk : Wv);
        val = s[l * 36864 + k * 192 + (n % 192)];
        if (n < 192) val *= 0.14433756729740643f;   // 1/sqrt(48) folded into Wq
    } else if (idx < WOFF_WF1) {                // Wo^T [192][192] x3
        int r = idx - WOFF_WO; int l = r / 36864; r %= 36864;
        int n = r / 192, k = r % 192;
        val = Wo[l * 36864 + k * 192 + n];
    } else if (idx < WOFF_WF2) {                // Wf1^T [384][192] x3
        int r = idx - WOFF_WF1; int l = r / 73728; r %= 73728;
        int n = r / 192, k = r % 192;
        val = Wf1[l * 73728 + k * 384 + n];
    } else if (idx < WOFF_HSD) {                // Wf2^T [192][384] x3
        int r = idx - WOFF_WF2; int l = r / 73728; r %= 73728;
        int n = r / 384, k = r % 384;
        val = Wf2[l * 73728 + k * 192 + n];
    } else if (idx < WOFF_WE2) {                // [Hs|Hd]^T [384][192]
        int r = idx - WOFF_HSD;
        int n = r / 192, k = r % 192;
        val = (n < 192) ? We1[k * 192 + n] : We1[(192 + k) * 192 + (n - 192)];
    } else {                                    // We2^T [96][192]
        int r = idx - WOFF_WE2;
        int n = r / 192, k = r % 192;
        val = We2[k * 96 + n];
    }
    wb[idx] = f2bf(val);
}

// LDS tile layout: row n holds k-block j (8 ushorts) at slot (j ^ (n&7)); row stride
// SBLK % 8 == 0 blocks -> stride 0 mod 32 dwords -> conflict-free fragment reads.

// ---------------- chunked MFMA GEMM (input proj / wo / ff2) ---------------------------
template <int EPI, int DUAL, int BN, int KCH, int TERMS>
__global__ __launch_bounds__(256, 2)
void mfma_gemm(const unsigned short* __restrict__ Ahi, const unsigned short* __restrict__ Alo,
               int M, int Ka,
               const unsigned short* __restrict__ B, const float* __restrict__ bias,
               const unsigned short* __restrict__ Rhi, const unsigned short* __restrict__ Rlo,
               const float* __restrict__ lng, const float* __restrict__ lnb,
               unsigned short* __restrict__ Chi, unsigned short* __restrict__ Clo, int ldc) {
    constexpr int NT = BN / 16;
    constexpr int JB = KCH / 8;
    constexpr int SBLK = ((JB + 7) / 8) * 8;
    __shared__ __align__(16) unsigned short sB[BN * SBLK * 8];
    const int tid = threadIdx.x;
    const int wave = tid >> 6, lane = tid & 63;
    const int quad = lane >> 4, l16 = lane & 15;
    const int rbase = blockIdx.x * 128;
    const int cbase = blockIdx.y * BN;

    floatx4 acc[2][NT];
#pragma unroll
    for (int mt = 0; mt < 2; ++mt)
#pragma unroll
        for (int nt = 0; nt < NT; ++nt) acc[mt][nt] = (floatx4)0.0f;

    const int r0 = min(rbase + wave * 32 + l16, M - 1);
    const int r1 = min(rbase + wave * 32 + 16 + l16, M - 1);
    const unsigned short* pa0h = Ahi + (size_t)r0 * Ka + quad * 8;
    const unsigned short* pa1h = Ahi + (size_t)r1 * Ka + quad * 8;
    const unsigned short* pa0l = Alo + (size_t)r0 * Ka + quad * 8;
    const unsigned short* pa1l = Alo + (size_t)r1 * Ka + quad * 8;

    for (int kb = 0; kb < Ka; kb += KCH) {
        if (kb) __syncthreads();
        for (int i = tid; i < BN * JB; i += 256) {
            int n = i % BN, j = i / BN;
            *(uint4*)&sB[(n * SBLK + (j ^ (n & 7))) * 8] =
                *(const uint4*)(B + (size_t)(cbase + n) * Ka + kb + j * 8);
        }
        __syncthreads();
        short8 ch0 = *(const short8*)(pa0h + kb);
        short8 ch1 = *(const short8*)(pa1h + kb);
        short8 cl0, cl1;
        if (TERMS == 2) {
            cl0 = *(const short8*)(pa0l + kb);
            cl1 = *(const short8*)(pa1l + kb);
        }
#pragma unroll
        for (int kc = 0; kc < KCH; kc += 32) {
            short8 nh0 = ch0, nh1 = ch1, nl0 = ch0, nl1 = ch1;
            if (kc + 32 < KCH) {
                nh0 = *(const short8*)(pa0h + kb + kc + 32);
                nh1 = *(const short8*)(pa1h + kb + kc + 32);
                if (TERMS == 2) {
                    nl0 = *(const short8*)(pa0l + kb + kc + 32);
                    nl1 = *(const short8*)(pa1l + kb + kc + 32);
                }
            }
            const int jbase = kc / 8;
#pragma unroll
            for (int nt = 0; nt < NT; ++nt) {
                int jj = (jbase + quad) ^ (l16 & 7);
                short8 b = *(const short8*)&sB[((nt * 16 + l16) * SBLK + jj) * 8];
                acc[0][nt] = mfma16(ch0, b, acc[0][nt]);
                if (TERMS == 2) acc[0][nt] = mfma16(cl0, b, acc[0][nt]);
                acc[1][nt] = mfma16(ch1, b, acc[1][nt]);
                if (TERMS == 2) acc[1][nt] = mfma16(cl1, b, acc[1][nt]);
            }
            ch0 = nh0; ch1 = nh1;
            if (TERMS == 2) { cl0 = nl0; cl1 = nl1; }
        }
    }

    float bb[NT], gg[NT], be[NT];
#pragma unroll
    for (int nt = 0; nt < NT; ++nt) {
        int colg = cbase + nt * 16 + l16;
        bb[nt] = bias ? bias[colg] : 0.f;
        if (EPI == 2) { gg[nt] = lng[colg]; be[nt] = lnb[colg]; }
    }
#pragma unroll
    for (int mt = 0; mt < 2; ++mt) {
#pragma unroll
        for (int reg = 0; reg < 4; ++reg) {
            int row = rbase + wave * 32 + mt * 16 + quad * 4 + reg;
            if (EPI == 2) {
                int rr = min(row, M - 1);
                float v[NT], s = 0.f, q = 0.f;
#pragma unroll
                for (int nt = 0; nt < NT; ++nt) {
                    size_t off = (size_t)rr * 192 + nt * 16 + l16;
                    float resid = bf2f(Rhi[off]) + bf2f(Rlo[off]);
                    v[nt] = acc[mt][nt][reg] + bb[nt] + resid;
                    s += v[nt]; q += v[nt] * v[nt];
                }
#pragma unroll
                for (int off = 1; off < 16; off <<= 1) {
                    s += __shfl_xor(s, off);
                    q += __shfl_xor(q, off);
                }
                float mean = s * (1.f / 192.f);
                float var = q * (1.f / 192.f) - mean * mean;
                float rs = rsqrtf(var + 1e-5f);
                if (row < M) {
#pragma unroll
                    for (int nt = 0; nt < NT; ++nt) {
                        float r = (v[nt] - mean) * rs * gg[nt] + be[nt];
                        unsigned short hi, lo;
                        split_bf16(r, hi, lo);
                        size_t off = (size_t)row * 192 + nt * 16 + l16;
                        Chi[off] = hi; Clo[off] = lo;
                    }
                }
            } else if (row < M) {
#pragma unroll
                for (int nt = 0; nt < NT; ++nt) {
                    float v = acc[mt][nt][reg] + bb[nt];
                    if (EPI == 1) v = fmaxf(v, 0.f);
                    size_t off = (size_t)row * ldc + cbase + nt * 16 + l16;
                    if (DUAL) {
                        unsigned short hi, lo;
                        split_bf16(v, hi, lo);
                        Chi[off] = hi; Clo[off] = lo;
                    } else {
                        Chi[off] = f2bf(v);
                    }
                }
            }
        }
    }
}

// ---------------- A-stationary MFMA GEMM (qkv / ff1 / hsd) ----------------------------
template <int EPI, int DUAL, int BN, int NTILES, int TERMS, int KF, int OUTMODE>
__global__ __launch_bounds__(256, 2)
void mfma_gemm_astat(const unsigned short* __restrict__ Ahi, const unsigned short* __restrict__ Alo,
                     int M, const unsigned short* __restrict__ B, const float* __restrict__ bias,
                     unsigned short* __restrict__ Chi, unsigned short* __restrict__ Clo, int ldc) {
    constexpr int NT = BN / 16;
    constexpr int Ka = KF * 32;
    constexpr int SBLK = KF * 4;
    __shared__ __align__(16) unsigned short sB[BN * SBLK * 8];
    const int tid = threadIdx.x;
    const int wave = tid >> 6, lane = tid & 63;
    const int quad = lane >> 4, l16 = lane & 15;
    const int rbase = blockIdx.x * 128;

    const int r0 = min(rbase + wave * 32 + l16, M - 1);
    const int r1 = min(rbase + wave * 32 + 16 + l16, M - 1);
    const unsigned short* pa0h = Ahi + (size_t)r0 * Ka + quad * 8;
    const unsigned short* pa1h = Ahi + (size_t)r1 * Ka + quad * 8;
    const unsigned short* pa0l = Alo + (size_t)r0 * Ka + quad * 8;
    const unsigned short* pa1l = Alo + (size_t)r1 * Ka + quad * 8;

    short8 afh[2][KF], afl[2][KF];
#pragma unroll
    for (int kf = 0; kf < KF; ++kf) {
        afh[0][kf] = *(const short8*)(pa0h + kf * 32);
        afh[1][kf] = *(const short8*)(pa1h + kf * 32);
        if (TERMS == 2) {
            afl[0][kf] = *(const short8*)(pa0l + kf * 32);
            afl[1][kf] = *(const short8*)(pa1l + kf * 32);
        }
    }

    for (int t = 0; t < NTILES; ++t) {
        const int cbase = t * BN;
        if (t) __syncthreads();
        for (int i = tid; i < BN * KF * 4; i += 256) {
            int n = i % BN, j = i / BN;
            *(uint4*)&sB[(n * SBLK + (j ^ (n & 7))) * 8] =
                *(const uint4*)(B + (size_t)(cbase + n) * Ka + j * 8);
        }
        __syncthreads();

        floatx4 acc[2][NT];
#pragma unroll
        for (int mt = 0; mt < 2; ++mt)
#pragma unroll
            for (int nt = 0; nt < NT; ++nt) acc[mt][nt] = (floatx4)0.0f;

#pragma unroll
        for (int kf = 0; kf < KF; ++kf) {
#pragma unroll
            for (int nt = 0; nt < NT; ++nt) {
                int jj = (kf * 4 + quad) ^ (l16 & 7);
                short8 b = *(const short8*)&sB[((nt * 16 + l16) * SBLK + jj) * 8];
                acc[0][nt] = mfma16(afh[0][kf], b, acc[0][nt]);
                if (TERMS == 2) acc[0][nt] = mfma16(afl[0][kf], b, acc[0][nt]);
                acc[1][nt] = mfma16(afh[1][kf], b, acc[1][nt]);
                if (TERMS == 2) acc[1][nt] = mfma16(afl[1][kf], b, acc[1][nt]);
            }
        }

        float bb[NT];
#pragma unroll
        for (int nt = 0; nt < NT; ++nt) bb[nt] = bias ? bias[cbase + nt * 16 + l16] : 0.f;
#pragma unroll
        for (int mt = 0; mt < 2; ++mt) {
#pragma unroll
            for (int reg = 0; reg < 4; ++reg) {
                int row = rbase + wave * 32 + mt * 16 + quad * 4 + reg;
                if (row < M) {
#pragma unroll
                    for (int nt = 0; nt < NT; ++nt) {
                        float v = acc[mt][nt][reg] + bb[nt];
                        if (EPI == 1) v = fmaxf(v, 0.f);
                        if (OUTMODE == 1) {
                            int c = cbase + nt * 16 + l16;
                            if (c < 192) {
                                Chi[(size_t)row * 192 + c] = f2bf(v);
                            } else {
                                int cc = c - 192;
                                int idx = (cc < 192) ? (cc * 2) : ((cc - 192) * 2 + 1);
                                Clo[(size_t)row * 384 + idx] = f2bf(v);
                            }
                        } else {
                            size_t off = (size_t)row * ldc + cbase + nt * 16 + l16;
                            if (DUAL) {
                                unsigned short hi, lo;
                                split_bf16(v, hi, lo);
                                Chi[off] = hi; Clo[off] = lo;
                            } else {
                                Chi[off] = f2bf(v);
                            }
                        }
                    }
                }
            }
        }
    }
}

// ---------------- edge attention (round-6 layout, msgH-only output) -------------------
// no-max softmax (exact, shift-invariant; logits O(3)); 4-edge unroll.
__global__ __launch_bounds__(256)
void attn_kernel(const unsigned short* __restrict__ qB, const unsigned short* __restrict__ kvB,
                 const float* __restrict__ ea, const float* __restrict__ We_l,
                 const int2* __restrict__ csr2, const int* __restrict__ row_ptr,
                 unsigned short* __restrict__ msg_hi) {
    __shared__ float sWe[768];
    const int tid = threadIdx.x;
    for (int i = tid; i < 768; i += 256) sWe[i] = We_l[i];
    __syncthreads();

    const int lane = tid & 63;
    const int node = blockIdx.x * 4 + (tid >> 6);
    const int d0 = (lane >> 4) * 48 + (lane & 15) * 3;

    float W[4][3];
#pragma unroll
    for (int w = 0; w < 4; ++w) {
        W[w][0] = sWe[w * 192 + d0];
        W[w][1] = sWe[w * 192 + d0 + 1];
        W[w][2] = sWe[w * 192 + d0 + 2];
    }
    size_t qoff = (size_t)node * 192 + d0;
    float q0 = bf2f(qB[qoff]), q1 = bf2f(qB[qoff + 1]), q2 = bf2f(qB[qoff + 2]);
    float qe0 = q0 * W[0][0] + q1 * W[0][1] + q2 * W[0][2];
    float qe1 = q0 * W[1][0] + q1 * W[1][1] + q2 * W[1][2];
    float qe2 = q0 * W[2][0] + q1 * W[2][1] + q2 * W[2][2];
    float qe3 = q0 * W[3][0] + q1 * W[3][1] + q2 * W[3][2];
#pragma unroll
    for (int off = 1; off < 16; off <<= 1) {
        qe0 += __shfl_xor(qe0, off);
        qe1 += __shfl_xor(qe1, off);
        qe2 += __shfl_xor(qe2, off);
        qe3 += __shfl_xor(qe3, off);
    }

    const unsigned int* kv = (const unsigned int*)kvB;
    const float4* ea4 = (const float4*)ea;

    float den = 0.f;
    float v0 = 0.f, v1 = 0.f, v2 = 0.f;
    float wa0 = 0.f, wa1 = 0.f, wa2 = 0.f, wa3 = 0.f;
    const int beg = row_ptr[node], end = row_ptr[node + 1];
    int p = beg;
    for (; p + 3 < end; p += 4) {
        int2 seA = csr2[p], seB = csr2[p + 1], seC = csr2[p + 2], seD = csr2[p + 3];
        size_t bA = (size_t)seA.x * 192 + d0;
        size_t bB = (size_t)seB.x * 192 + d0;
        size_t bC = (size_t)seC.x * 192 + d0;
        size_t bD = (size_t)seD.x * 192 + d0;
        unsigned int uA0 = kv[bA], uA1 = kv[bA + 1], uA2 = kv[bA + 2];
        unsigned int uB0 = kv[bB], uB1 = kv[bB + 1], uB2 = kv[bB + 2];
        unsigned int uC0 = kv[bC], uC1 = kv[bC + 1], uC2 = kv[bC + 2];
        unsigned int uD0 = kv[bD], uD1 = kv[bD + 1], uD2 = kv[bD + 2];
        float4 wA = ea4[seA.y], wB = ea4[seB.y], wC = ea4[seC.y], wD = ea4[seD.y];
        float dA = q0 * bf2f((unsigned short)uA0) + q1 * bf2f((unsigned short)uA1) + q2 * bf2f((unsigned short)uA2);
        float dB = q0 * bf2f((unsigned short)uB0) + q1 * bf2f((unsigned short)uB1) + q2 * bf2f((unsigned short)uB2);
        float dC = q0 * bf2f((unsigned short)uC0) + q1 * bf2f((unsigned short)uC1) + q2 * bf2f((unsigned short)uC2);
        float dD = q0 * bf2f((unsigned short)uD0) + q1 * bf2f((unsigned short)uD1) + q2 * bf2f((unsigned short)uD2);
#pragma unroll
        for (int off = 1; off < 16; off <<= 1) {
            dA += __shfl_xor(dA, off);
            dB += __shfl_xor(dB, off);
            dC += __shfl_xor(dC, off);
            dD += __shfl_xor(dD, off);
        }
        float pA = __expf(dA + wA.x * qe0 + wA.y * qe1 + wA.z * qe2 + wA.w * qe3);
        float pB = __expf(dB + wB.x * qe0 + wB.y * qe1 + wB.z * qe2 + wB.w * qe3);
        float pC = __expf(dC + wC.x * qe0 + wC.y * qe1 + wC.z * qe2 + wC.w * qe3);
        float pD = __expf(dD + wD.x * qe0 + wD.y * qe1 + wD.z * qe2 + wD.w * qe3);
        den += pA + pB + pC + pD;
        v0 += pA * bf2f((unsigned short)(uA0 >> 16)) + pB * bf2f((unsigned short)(uB0 >> 16))
            + pC * bf2f((unsigned short)(uC0 >> 16)) + pD * bf2f((unsigned short)(uD0 >> 16));
        v1 += pA * bf2f((unsigned short)(uA1 >> 16)) + pB * bf2f((unsigned short)(uB1 >> 16))
            + pC * bf2f((unsigned short)(uC1 >> 16)) + pD * bf2f((unsigned short)(uD1 >> 16));
        v2 += pA * bf2f((unsigned short)(uA2 >> 16)) + pB * bf2f((unsigned short)(uB2 >> 16))
            + pC * bf2f((unsigned short)(uC2 >> 16)) + pD * bf2f((unsigned short)(uD2 >> 16));
        wa0 += pA * wA.x + pB * wB.x + pC * wC.x + pD * wD.x;
        wa1 += pA * wA.y + pB * wB.y + pC * wC.y + pD * wD.y;
        wa2 += pA * wA.z + pB * wB.z + pC * wC.z + pD * wD.z;
        wa3 += pA * wA.w + pB * wB.w + pC * wC.w + pD * wD.w;
    }
    for (; p < end; ++p) {
        int2 se = csr2[p];
        size_t b = (size_t)se.x * 192 + d0;
        unsigned int u0 = kv[b], u1 = kv[b + 1], u2 = kv[b + 2];
        float4 w = ea4[se.y];
        float d = q0 * bf2f((unsigned short)u0) + q1 * bf2f((unsigned short)u1)
                + q2 * bf2f((unsigned short)u2);
#pragma unroll
        for (int off = 1; off < 16; off <<= 1) d += __shfl_xor(d, off);
        float pe = __expf(d + w.x * qe0 + w.y * qe1 + w.z * qe2 + w.w * qe3);
        den += pe;
        v0 += pe * bf2f((unsigned short)(u0 >> 16));
        v1 += pe * bf2f((unsigned short)(u1 >> 16));
        v2 += pe * bf2f((unsigned short)(u2 >> 16));
        wa0 += pe * w.x;
        wa1 += pe * w.y;
        wa2 += pe * w.z;
        wa3 += pe * w.w;
    }
    float inv = 1.f / (den + 1e-16f);
    float m0 = (v0 + wa0 * W[0][0] + wa1 * W[1][0] + wa2 * W[2][0] + wa3 * W[3][0]) * inv;
    float m1 = (v1 + wa0 * W[0][1] + wa1 * W[1][1] + wa2 * W[2][1] + wa3 * W[3][1]) * inv;
    float m2 = (v2 + wa0 * W[0][2] + wa1 * W[1][2] + wa2 * W[2][2] + wa3 * W[3][2]) * inv;
    size_t ob = (size_t)node * 192 + d0;
    msg_hi[ob]     = f2bf(m0);
    msg_hi[ob + 1] = f2bf(m1);
    msg_hi[ob + 2] = f2bf(m2);
}

// ---------------- edge head: 128 edges/block (32/wave), swizzled sW LDS ---------------
// Lane (quad,l16) owns edges {base+l16, base+16+l16}, cols quad*8+j: exact A-fragments.
// sW staged once (36.9 KB), amortized over 2x MFMA work; two independent acc chains.
__global__ __launch_bounds__(256, 2)
void edge_head_kernel(const unsigned short* __restrict__ hsd, const float* __restrict__ ea,
                      const int* __restrict__ src, const int* __restrict__ dst,
                      const float* __restrict__ W1e, const float* __restrict__ b1,
                      const unsigned short* __restrict__ W2hi,
                      const float* __restrict__ b2, const float* __restrict__ W3,
                      const float* __restrict__ b3, float* __restrict__ out) {
    __shared__ __align__(16) unsigned short sW[96 * 192];   // SBLK=24 blocks, swizzled
    __shared__ __align__(16) float sWe1[768];
    __shared__ __align__(16) float sB1[192];
    const int tid = threadIdx.x;
    const int wave = tid >> 6, lane = tid & 63;
    const int quad = lane >> 4, l16 = lane & 15;
    const int ebase = blockIdx.x * 128;

    for (int i = tid; i < 768; i += 256) sWe1[i] = W1e[i];
    if (tid < 192) sB1[tid] = b1[tid];
    for (int i = tid; i < 96 * 24; i += 256) {
        int n = i % 96, j = i / 96;
        *(uint4*)&sW[(n * 24 + (j ^ (n & 7))) * 8] = *(const uint4*)(W2hi + (size_t)n * 192 + j * 8);
    }

    const int e0 = ebase + wave * 32 + l16;       // group-0 edge
    const int e1 = e0 + 16;                       // group-1 edge
    const int s0 = src[e0], d0n = dst[e0];
    const int s1 = src[e1], d1n = dst[e1];
    const float4 eav0 = *(const float4*)(ea + (size_t)e0 * 4);
    const float4 eav1 = *(const float4*)(ea + (size_t)e1 * 4);
    const unsigned short* hs0_p = hsd + (size_t)s0 * 384 + quad * 8;
    const unsigned short* hd0_p = hsd + (size_t)d0n * 384 + 192 + quad * 8;
    const unsigned short* hs1_p = hsd + (size_t)s1 * 384 + quad * 8;
    const unsigned short* hd1_p = hsd + (size_t)d1n * 384 + 192 + quad * 8;

    floatx4 acc[2][6];
#pragma unroll
    for (int g = 0; g < 2; ++g)
#pragma unroll
        for (int nt = 0; nt < 6; ++nt) acc[g][nt] = (floatx4)0.0f;
    __syncthreads();

    ushort8 hs0_c = *(const ushort8*)hs0_p;
    ushort8 hd0_c = *(const ushort8*)hd0_p;
    ushort8 hs1_c = *(const ushort8*)hs1_p;
    ushort8 hd1_c = *(const ushort8*)hd1_p;
#pragma unroll
    for (int kc = 0; kc < 192; kc += 32) {
        ushort8 hs0_n = hs0_c, hd0_n = hd0_c, hs1_n = hs1_c, hd1_n = hd1_c;
        if (kc + 32 < 192) {
            hs0_n = *(const ushort8*)(hs0_p + kc + 32);
            hd0_n = *(const ushort8*)(hd0_p + kc + 32);
            hs1_n = *(const ushort8*)(hs1_p + kc + 32);
            hd1_n = *(const ushort8*)(hd1_p + kc + 32);
        }
        const int c0 = kc + quad * 8;
        float wb1[8], w0v[8], w1v[8], w2v[8], w3v[8];
        *(float4*)&wb1[0] = *(const float4*)&sB1[c0];
        *(float4*)&wb1[4] = *(const float4*)&sB1[c0 + 4];
        *(float4*)&w0v[0] = *(const float4*)&sWe1[c0];
        *(float4*)&w0v[4] = *(const float4*)&sWe1[c0 + 4];
        *(float4*)&w1v[0] = *(const float4*)&sWe1[192 + c0];
        *(float4*)&w1v[4] = *(const float4*)&sWe1[192 + c0 + 4];
        *(float4*)&w2v[0] = *(const float4*)&sWe1[384 + c0];
        *(float4*)&w2v[4] = *(const float4*)&sWe1[384 + c0 + 4];
        *(float4*)&w3v[0] = *(const float4*)&sWe1[576 + c0];
        *(float4*)&w3v[4] = *(const float4*)&sWe1[576 + c0 + 4];
        ushort8 ah0, ah1;
#pragma unroll
        for (int j = 0; j < 8; ++j) {
            float base = wb1[j];
            float ce0 = base + eav0.x * w0v[j] + eav0.y * w1v[j]
                      + eav0.z * w2v[j] + eav0.w * w3v[j];
            float ce1 = base + eav1.x * w0v[j] + eav1.y * w1v[j]
                      + eav1.z * w2v[j] + eav1.w * w3v[j];
            ah0[j] = f2bf(fmaxf(bf2f(hs0_c[j]) + bf2f(hd0_c[j]) + ce0, 0.f));
            ah1[j] = f2bf(fmaxf(bf2f(hs1_c[j]) + bf2f(hd1_c[j]) + ce1, 0.f));
        }
        short8 a0 = *(short8*)&ah0, a1 = *(short8*)&ah1;
        const int jbase = kc / 8;
#pragma unroll
        for (int nt = 0; nt < 6; ++nt) {
            int jj = (jbase + quad) ^ (l16 & 7);
            short8 bh = *(const short8*)&sW[((nt * 16 + l16) * 24 + jj) * 8];
            acc[0][nt] = mfma16(a0, bh, acc[0][nt]);
            acc[1][nt] = mfma16(a1, bh, acc[1][nt]);
        }
        hs0_c = hs0_n; hd0_c = hd0_n; hs1_c = hs1_n; hd1_c = hd1_n;
    }

    float w3[6], bb2[6];
#pragma unroll
    for (int nt = 0; nt < 6; ++nt) {
        int col = nt * 16 + l16;
        w3[nt] = W3[col];
        bb2[nt] = b2[col];
    }
    float b3v = b3[0];
#pragma unroll
    for (int g = 0; g < 2; ++g) {
#pragma unroll
        for (int reg = 0; reg < 4; ++reg) {
            float sacc = 0.f;
#pragma unroll
            for (int nt = 0; nt < 6; ++nt) {
                float z = fmaxf(acc[g][nt][reg] + bb2[nt], 0.f);
                sacc = fmaf(z, w3[nt], sacc);
            }
#pragma unroll
            for (int off = 1; off < 16; off <<= 1) sacc += __shfl_xor(sacc, off);
            if (l16 == 0) out[ebase + wave * 32 + g * 16 + quad * 4 + reg] = sacc + b3v;
        }
    }
}

extern "C" void kernel_launch(void* const* d_in, const int* in_sizes, int n_in,
                              void* d_out, int out_size, void* d_ws, size_t ws_size,
                              hipStream_t stream) {
    const float* x     = (const float*)d_in[0];
    const int*   eidx  = (const int*)d_in[1];
    const float* ea    = (const float*)d_in[2];
    const int*   batch = (const int*)d_in[3];
    const int*   gptr  = (const int*)d_in[4];
    const int*   tgid  = (const int*)d_in[5];
    const float* gp    = (const float*)d_in[6];
    const float* sp    = (const float*)d_in[7];
    const float* epp   = (const float*)d_in[8];
    const float* W_in  = (const float*)d_in[9];
    const float* b_in  = (const float*)d_in[10];
    const float* Wq    = (const float*)d_in[11];
    const float* Wk    = (const float*)d_in[12];
    const float* Wv    = (const float*)d_in[13];
    const float* We    = (const float*)d_in[14];
    const float* Wo    = (const float*)d_in[15];
    const float* bo    = (const float*)d_in[16];
    const float* ln1g  = (const float*)d_in[17];
    const float* ln1b  = (const float*)d_in[18];
    const float* Wf1   = (const float*)d_in[19];
    const float* bf1   = (const float*)d_in[20];
    const float* Wf2   = (const float*)d_in[21];
    const float* bf2   = (const float*)d_in[22];
    const float* ln2g  = (const float*)d_in[23];
    const float* ln2b  = (const float*)d_in[24];
    const float* We1   = (const float*)d_in[25];
    const float* be1   = (const float*)d_in[26];
    const float* We2   = (const float*)d_in[27];
    const float* be2   = (const float*)d_in[28];
    const float* We3   = (const float*)d_in[29];
    const float* be3   = (const float*)d_in[30];
    const int* src = eidx;
    const int* dst = eidx + N_EDGES;

    unsigned short* ub = (unsigned short*)d_ws;
    unsigned short* featH = ub;                  // 40000*32
    unsigned short* featL = ub + 1280000;
    unsigned short* hH    = ub + 2560000;        // 40000*192 each
    unsigned short* hL    = ub + 10240000;
    unsigned short* htH   = ub + 17920000;
    unsigned short* htL   = ub + 25600000;
    unsigned short* msgH  = ub + 33280000;
    unsigned short* rbuf  = ub + 48640000;       // 40000*768 region
    unsigned short* qB    = rbuf;                // 40000*192
    unsigned short* kvB   = rbuf + 7680000;      // 40000*384 interleaved k/v
    unsigned short* ffH   = rbuf;                // 40000*384 (after attn)
    unsigned short* hsdB  = rbuf;                // 40000*384
    unsigned short* wb    = ub + 79360000;       // WTOT
    int* ib   = (int*)(ub + 80343040);
    int* cnt  = ib;
    int* rowp = ib + 40000;
    int* curs = ib + 80004;
    int2* csr2 = (int2*)(ib + 120004);
    int* bsum  = ib + 920004;
    int* boffs = ib + 920044;

    hipMemsetAsync(cnt, 0, N_NODES * sizeof(int), stream);
    count_kernel<<<1563, 256, 0, stream>>>(dst, cnt, N_EDGES);
    scan1_kernel<<<40, 1024, 0, stream>>>(cnt, rowp, bsum, N_NODES);
    scan2_kernel<<<1, 64, 0, stream>>>(bsum, boffs, rowp, 40, N_NODES);
    scan3_kernel<<<40, 1024, 0, stream>>>(rowp, curs, boffs, N_NODES);
    scatter_kernel<<<1563, 256, 0, stream>>>(src, dst, curs, csr2, N_EDGES);
    feat_kernel<<<5000, 256, 0, stream>>>(x, batch, gptr, tgid, gp, sp, epp, featH, featL, N_NODES);
    prep_kernel<<<3840, 256, 0, stream>>>(W_in, Wq, Wk, Wv, Wo, Wf1, Wf2, We1, We2, wb);

    dim3 blk(256);
    // input projection: feat[40000, K=32 planes] @ W_in -> h planes (chunked path)
    mfma_gemm<0, 1, 96, 32, 2><<<dim3(313, 2), blk, 0, stream>>>(featH, featL, N_NODES, 32,
        wb + WOFF_WIN, b_in, nullptr, nullptr, nullptr, nullptr, hH, hL, 192);

    for (int l = 0; l < 3; ++l) {
        const unsigned short* wq = wb + WOFF_QKV + l * 110592;
        // fused qkv, A-stationary: q -> qB, k/v -> kvB interleaved (single-term A)
        mfma_gemm_astat<0, 0, 96, 6, 1, 6, 1><<<313, blk, 0, stream>>>(hH, hL, N_NODES,
            wq, nullptr, qB, kvB, 0);
        attn_kernel<<<10000, blk, 0, stream>>>(qB, kvB, ea, We + l * 768, csr2, rowp, msgH);
        // wo + residual + LN (msg single-plane -> TERMS=1); KCH=64 for occupancy
        mfma_gemm<2, 1, 192, 64, 1><<<dim3(313, 1), blk, 0, stream>>>(msgH, msgH, N_NODES, 192,
            wb + WOFF_WO + l * 36864, bo + l * 192, hH, hL, ln1g + l * 192, ln1b + l * 192,
            htH, htL, 192);
        // ff1: relu, single-plane output
        mfma_gemm_astat<1, 0, 96, 4, 2, 6, 0><<<313, blk, 0, stream>>>(htH, htL, N_NODES,
            wb + WOFF_WF1 + l * 73728, bf1 + l * 384, ffH, nullptr, 384);
        // ff2 + residual + LN (ff single-plane -> TERMS=1); KCH=64 for occupancy
        mfma_gemm<2, 1, 192, 64, 1><<<dim3(313, 1), blk, 0, stream>>>(ffH, ffH, N_NODES, 384,
            wb + WOFF_WF2 + l * 73728, bf2 + l * 192, htH, htL, ln2g + l * 192, ln2b + l * 192,
            hH, hL, 192);
    }

    // edge head pre-projections, A-stationary: [Hs|Hd] -> hsdB bf16 [N,384]
    mfma_gemm_astat<0, 0, 96, 4, 2, 6, 0><<<313, blk, 0, stream>>>(hH, hL, N_NODES,
        wb + WOFF_HSD, nullptr, hsdB, nullptr, 384);
    edge_head_kernel<<<3125, blk, 0, stream>>>(hsdB, ea, src, dst,
        We1 + 384 * 192, be1, wb + WOFF_WE2, be2, We3, be3, (float*)d_out);
}

// Round 11
// 831.427 us; speedup vs baseline: 1.1044x; 1.0291x over previous
//
#include <hip/hip_runtime.h>
#include <hip/hip_bf16.h>
#include <math.h>

#define N_NODES 40000
#define N_EDGES 400000
#define GCLIP 511

using short8  = __attribute__((ext_vector_type(8))) short;
using ushort8 = __attribute__((ext_vector_type(8))) unsigned short;
using floatx4 = __attribute__((ext_vector_type(4))) float;

__device__ __forceinline__ void split_bf16(float v, unsigned short& hi, unsigned short& lo) {
    __hip_bfloat16 h = __float2bfloat16(v);
    float r = v - __bfloat162float(h);
    __hip_bfloat16 l = __float2bfloat16(r);
    hi = *(unsigned short*)&h;
    lo = *(unsigned short*)&l;
}
__device__ __forceinline__ unsigned short f2bf(float f) {
    __hip_bfloat16 h = __float2bfloat16(f);
    return *(unsigned short*)&h;
}
__device__ __forceinline__ float bf2f(unsigned short u) {
    __hip_bfloat16 h = *(__hip_bfloat16*)&u;
    return __bfloat162float(h);
}
__device__ __forceinline__ floatx4 mfma16(short8 a, short8 b, floatx4 c) {
    return __builtin_amdgcn_mfma_f32_16x16x32_bf16(a, b, c, 0, 0, 0);
}

// ---------------- CSR build ----------------
__global__ void count_kernel(const int* __restrict__ dst, int* __restrict__ cnt, int E) {
    int e = blockIdx.x * 256 + threadIdx.x;
    if (e < E) atomicAdd(&cnt[dst[e]], 1);
}

__global__ void scan1_kernel(const int* __restrict__ cnt, int* __restrict__ rowp,
                             int* __restrict__ bsum, int n) {
    __shared__ int wsum[16];
    __shared__ int woff[16];
    int tid = threadIdx.x, wave = tid >> 6, lane = tid & 63;
    int i = blockIdx.x * 1024 + tid;
    int v = (i < n) ? cnt[i] : 0;
    int x = v;
    for (int off = 1; off < 64; off <<= 1) {
        int t = __shfl_up(x, off);
        if (lane >= off) x += t;
    }
    if (lane == 63) wsum[wave] = x;
    __syncthreads();
    if (wave == 0 && lane < 16) {
        int s = wsum[lane];
        for (int off = 1; off < 16; off <<= 1) {
            int t = __shfl_up(s, off);
            if (lane >= off) s += t;
        }
        woff[lane] = s;
    }
    __syncthreads();
    int incl = x + ((wave == 0) ? 0 : woff[wave - 1]);
    if (i < n) rowp[i] = incl - v;
    if (tid == 1023) bsum[blockIdx.x] = incl;
}

__global__ void scan2_kernel(const int* __restrict__ bsum, int* __restrict__ boffs,
                             int* __restrict__ rowp, int nb, int n) {
    int lane = threadIdx.x;
    int v = (lane < nb) ? bsum[lane] : 0;
    int x = v;
    for (int off = 1; off < 64; off <<= 1) {
        int t = __shfl_up(x, off);
        if (lane >= off) x += t;
    }
    if (lane < nb) boffs[lane] = x - v;
    if (lane == nb - 1) rowp[n] = x;
}

__global__ void scan3_kernel(int* __restrict__ rowp, int* __restrict__ curs,
                             const int* __restrict__ boffs, int n) {
    int i = blockIdx.x * 1024 + threadIdx.x;
    if (i < n) {
        int v = rowp[i] + boffs[blockIdx.x];
        rowp[i] = v;
        curs[i] = v;
    }
}

__global__ void scatter_kernel(const int* __restrict__ src, const int* __restrict__ dst,
                               int* __restrict__ cursor, int2* __restrict__ csr2, int E) {
    int e = blockIdx.x * 256 + threadIdx.x;
    if (e < E) {
        int pos = atomicAdd(&cursor[dst[e]], 1);
        csr2[pos] = make_int2(src[e], e);
    }
}

// ---------------- feature build -> bf16 hi/lo planes [N][32] (cols 16..31 zero) -------
__global__ void feat_kernel(const float* __restrict__ x, const int* __restrict__ batch,
                            const int* __restrict__ gptr, const int* __restrict__ tgid,
                            const float* __restrict__ gp, const float* __restrict__ sp,
                            const float* __restrict__ ep,
                            unsigned short* __restrict__ fhi, unsigned short* __restrict__ flo,
                            int n) {
    int idx = blockIdx.x * 256 + threadIdx.x;
    if (idx >= n * 32) return;
    int node = idx >> 5, c = idx & 31;
    float v = 0.f;
    if (c < 4) {
        v = x[node * 4 + c];
    } else if (c < 7) {
        int gid = gptr[batch[node]] + tgid[node];
        gid = min(max(gid, 0), GCLIP);
        v = gp[gid * 3 + (c - 4)];
    } else if (c < 10) {
        v = sp[node * 3 + (c - 7)];
    } else if (c < 16) {
        int gid = gptr[batch[node]] + tgid[node];
        gid = min(max(gid, 0), GCLIP);
        v = ep[gid * 6 + (c - 10)];
    }
    unsigned short hi, lo;
    split_bf16(v, hi, lo);
    fhi[idx] = hi;
    flo[idx] = lo;
}

// ---------------- weight prep: transpose to [Nrows][Ka] bf16 (hi only) ----------------
#define WOFF_WIN 0
#define WOFF_QKV 6144
#define WOFF_WO  337920
#define WOFF_WF1 448512
#define WOFF_WF2 669696
#define WOFF_HSD 890880
#define WOFF_WE2 964608
#define WTOT     983040

__global__ void prep_kernel(const float* __restrict__ W_in, const float* __restrict__ Wq,
                            const float* __restrict__ Wk, const float* __restrict__ Wv,
                            const float* __restrict__ Wo, const float* __restrict__ Wf1,
                            const float* __restrict__ Wf2, const float* __restrict__ We1,
                            const float* __restrict__ We2, unsigned short* __restrict__ wb) {
    int idx = blockIdx.x * 256 + threadIdx.x;
    if (idx >= WTOT) return;
    float val;
    if (idx < WOFF_QKV) {                       // W_in^T [192][32], K=16 padded
        int n = idx / 32, k = idx % 32;
        val = (k < 16) ? W_in[k * 192 + n] : 0.f;
    } else if (idx < WOFF_WO) {                 // Wqkv^T [576][192] x3; q rows pre-scaled
        int r = idx - WOFF_QKV; int l = r / 110592; r %= 110592;
        int n = r / 192, k = r % 192;
        const float* s = (n < 192) ? Wq : (n < 384 ? Wk : Wv);
        val = s[l * 36864 + k * 192 + (n % 192)];
        if (n < 192) val *= 0.14433756729740643f;   // 1/sqrt(48) folded into Wq
    } else if (idx < WOFF_WF1) {                // Wo^T [192][192] x3
        int r = idx - WOFF_WO; int l = r / 36864; r %= 36864;
        int n = r / 192, k = r % 192;
        val = Wo[l * 36864 + k * 192 + n];
    } else if (idx < WOFF_WF2) {                // Wf1^T [384][192] x3
        int r = idx - WOFF_WF1; int l = r / 73728; r %= 73728;
        int n = r / 192, k = r % 192;
        val = Wf1[l * 73728 + k * 384 + n];
    } else if (idx < WOFF_HSD) {                // Wf2^T [192][384] x3
        int r = idx - WOFF_WF2; int l = r / 73728; r %= 73728;
        int n = r / 384, k = r % 384;
        val = Wf2[l * 73728 + k * 192 + n];
    } else if (idx < WOFF_WE2) {                // [Hs|Hd]^T [384][192]
        int r = idx - WOFF_HSD;
        int n = r / 192, k = r % 192;
        val = (n < 192) ? We1[k * 192 + n] : We1[(192 + k) * 192 + (n - 192)];
    } else {                                    // We2^T [96][192]
        int r = idx - WOFF_WE2;
        int n = r / 192, k = r % 192;
        val = We2[k * 96 + n];
    }
    wb[idx] = f2bf(val);
}

// LDS tile layout: row n holds k-block j (8 ushorts) at slot (j ^ (n&7)); row stride
// SBLK % 8 == 0 blocks -> stride 0 mod 32 dwords -> conflict-free fragment reads.

// ---------------- chunked MFMA GEMM (input proj / wo / ff2) ---------------------------
// BM = 64*MT (4 waves x 16*MT rows). MT=1 -> 625 blocks for M=40000 (tail balance).
template <int EPI, int DUAL, int BN, int KCH, int TERMS, int MT>
__global__ __launch_bounds__(256, 4)
void mfma_gemm(const unsigned short* __restrict__ Ahi, const unsigned short* __restrict__ Alo,
               int M, int Ka,
               const unsigned short* __restrict__ B, const float* __restrict__ bias,
               const unsigned short* __restrict__ Rhi, const unsigned short* __restrict__ Rlo,
               const float* __restrict__ lng, const float* __restrict__ lnb,
               unsigned short* __restrict__ Chi, unsigned short* __restrict__ Clo, int ldc) {
    constexpr int NT = BN / 16;
    constexpr int JB = KCH / 8;
    constexpr int SBLK = ((JB + 7) / 8) * 8;
    __shared__ __align__(16) unsigned short sB[BN * SBLK * 8];
    const int tid = threadIdx.x;
    const int wave = tid >> 6, lane = tid & 63;
    const int quad = lane >> 4, l16 = lane & 15;
    const int rbase = blockIdx.x * 64 * MT;
    const int cbase = blockIdx.y * BN;

    floatx4 acc[MT][NT];
#pragma unroll
    for (int mt = 0; mt < MT; ++mt)
#pragma unroll
        for (int nt = 0; nt < NT; ++nt) acc[mt][nt] = (floatx4)0.0f;

    const unsigned short* pah[MT];
    const unsigned short* pal[MT];
#pragma unroll
    for (int mt = 0; mt < MT; ++mt) {
        int r = min(rbase + wave * 16 * MT + mt * 16 + l16, M - 1);
        pah[mt] = Ahi + (size_t)r * Ka + quad * 8;
        pal[mt] = Alo + (size_t)r * Ka + quad * 8;
    }

    for (int kb = 0; kb < Ka; kb += KCH) {
        if (kb) __syncthreads();
        for (int i = tid; i < BN * JB; i += 256) {
            int n = i % BN, j = i / BN;
            *(uint4*)&sB[(n * SBLK + (j ^ (n & 7))) * 8] =
                *(const uint4*)(B + (size_t)(cbase + n) * Ka + kb + j * 8);
        }
        __syncthreads();
        short8 ch[MT], cl[MT];
#pragma unroll
        for (int mt = 0; mt < MT; ++mt) {
            ch[mt] = *(const short8*)(pah[mt] + kb);
            if (TERMS == 2) cl[mt] = *(const short8*)(pal[mt] + kb);
        }
#pragma unroll
        for (int kc = 0; kc < KCH; kc += 32) {
            short8 nh[MT], nl[MT];
#pragma unroll
            for (int mt = 0; mt < MT; ++mt) { nh[mt] = ch[mt]; nl[mt] = ch[mt]; }
            if (kc + 32 < KCH) {
#pragma unroll
                for (int mt = 0; mt < MT; ++mt) {
                    nh[mt] = *(const short8*)(pah[mt] + kb + kc + 32);
                    if (TERMS == 2) nl[mt] = *(const short8*)(pal[mt] + kb + kc + 32);
                }
            }
            const int jbase = kc / 8;
#pragma unroll
            for (int nt = 0; nt < NT; ++nt) {
                int jj = (jbase + quad) ^ (l16 & 7);
                short8 b = *(const short8*)&sB[((nt * 16 + l16) * SBLK + jj) * 8];
#pragma unroll
                for (int mt = 0; mt < MT; ++mt) {
                    acc[mt][nt] = mfma16(ch[mt], b, acc[mt][nt]);
                    if (TERMS == 2) acc[mt][nt] = mfma16(cl[mt], b, acc[mt][nt]);
                }
            }
#pragma unroll
            for (int mt = 0; mt < MT; ++mt) {
                ch[mt] = nh[mt];
                if (TERMS == 2) cl[mt] = nl[mt];
            }
        }
    }

    float bb[NT], gg[NT], be[NT];
#pragma unroll
    for (int nt = 0; nt < NT; ++nt) {
        int colg = cbase + nt * 16 + l16;
        bb[nt] = bias ? bias[colg] : 0.f;
        if (EPI == 2) { gg[nt] = lng[colg]; be[nt] = lnb[colg]; }
    }
#pragma unroll
    for (int mt = 0; mt < MT; ++mt) {
#pragma unroll
        for (int reg = 0; reg < 4; ++reg) {
            int row = rbase + wave * 16 * MT + mt * 16 + quad * 4 + reg;
            if (EPI == 2) {
                int rr = min(row, M - 1);
                float v[NT], s = 0.f, q = 0.f;
#pragma unroll
                for (int nt = 0; nt < NT; ++nt) {
                    size_t off = (size_t)rr * 192 + nt * 16 + l16;
                    float resid = bf2f(Rhi[off]) + bf2f(Rlo[off]);
                    v[nt] = acc[mt][nt][reg] + bb[nt] + resid;
                    s += v[nt]; q += v[nt] * v[nt];
                }
#pragma unroll
                for (int off = 1; off < 16; off <<= 1) {
                    s += __shfl_xor(s, off);
                    q += __shfl_xor(q, off);
                }
                float mean = s * (1.f / 192.f);
                float var = q * (1.f / 192.f) - mean * mean;
                float rs = rsqrtf(var + 1e-5f);
                if (row < M) {
#pragma unroll
                    for (int nt = 0; nt < NT; ++nt) {
                        float r = (v[nt] - mean) * rs * gg[nt] + be[nt];
                        unsigned short hi, lo;
                        split_bf16(r, hi, lo);
                        size_t off = (size_t)row * 192 + nt * 16 + l16;
                        Chi[off] = hi; Clo[off] = lo;
                    }
                }
            } else if (row < M) {
#pragma unroll
                for (int nt = 0; nt < NT; ++nt) {
                    float v = acc[mt][nt][reg] + bb[nt];
                    if (EPI == 1) v = fmaxf(v, 0.f);
                    size_t off = (size_t)row * ldc + cbase + nt * 16 + l16;
                    if (DUAL) {
                        unsigned short hi, lo;
                        split_bf16(v, hi, lo);
                        Chi[off] = hi; Clo[off] = lo;
                    } else {
                        Chi[off] = f2bf(v);
                    }
                }
            }
        }
    }
}

// ---------------- A-stationary MFMA GEMM (qkv / ff1 / hsd), BM = 64*MT ----------------
template <int EPI, int DUAL, int BN, int NTILES, int TERMS, int KF, int OUTMODE, int MT>
__global__ __launch_bounds__(256, 4)
void mfma_gemm_astat(const unsigned short* __restrict__ Ahi, const unsigned short* __restrict__ Alo,
                     int M, const unsigned short* __restrict__ B, const float* __restrict__ bias,
                     unsigned short* __restrict__ Chi, unsigned short* __restrict__ Clo, int ldc) {
    constexpr int NT = BN / 16;
    constexpr int Ka = KF * 32;
    constexpr int SBLK = KF * 4;
    __shared__ __align__(16) unsigned short sB[BN * SBLK * 8];
    const int tid = threadIdx.x;
    const int wave = tid >> 6, lane = tid & 63;
    const int quad = lane >> 4, l16 = lane & 15;
    const int rbase = blockIdx.x * 64 * MT;

    short8 afh[MT][KF], afl[MT][KF];
#pragma unroll
    for (int mt = 0; mt < MT; ++mt) {
        int r = min(rbase + wave * 16 * MT + mt * 16 + l16, M - 1);
        const unsigned short* ph = Ahi + (size_t)r * Ka + quad * 8;
        const unsigned short* pl = Alo + (size_t)r * Ka + quad * 8;
#pragma unroll
        for (int kf = 0; kf < KF; ++kf) {
            afh[mt][kf] = *(const short8*)(ph + kf * 32);
            if (TERMS == 2) afl[mt][kf] = *(const short8*)(pl + kf * 32);
        }
    }

    for (int t = 0; t < NTILES; ++t) {
        const int cbase = t * BN;
        if (t) __syncthreads();
        for (int i = tid; i < BN * KF * 4; i += 256) {
            int n = i % BN, j = i / BN;
            *(uint4*)&sB[(n * SBLK + (j ^ (n & 7))) * 8] =
                *(const uint4*)(B + (size_t)(cbase + n) * Ka + j * 8);
        }
        __syncthreads();

        floatx4 acc[MT][NT];
#pragma unroll
        for (int mt = 0; mt < MT; ++mt)
#pragma unroll
            for (int nt = 0; nt < NT; ++nt) acc[mt][nt] = (floatx4)0.0f;

#pragma unroll
        for (int kf = 0; kf < KF; ++kf) {
#pragma unroll
            for (int nt = 0; nt < NT; ++nt) {
                int jj = (kf * 4 + quad) ^ (l16 & 7);
                short8 b = *(const short8*)&sB[((nt * 16 + l16) * SBLK + jj) * 8];
#pragma unroll
                for (int mt = 0; mt < MT; ++mt) {
                    acc[mt][nt] = mfma16(afh[mt][kf], b, acc[mt][nt]);
                    if (TERMS == 2) acc[mt][nt] = mfma16(afl[mt][kf], b, acc[mt][nt]);
                }
            }
        }

        float bb[NT];
#pragma unroll
        for (int nt = 0; nt < NT; ++nt) bb[nt] = bias ? bias[cbase + nt * 16 + l16] : 0.f;
#pragma unroll
        for (int mt = 0; mt < MT; ++mt) {
#pragma unroll
            for (int reg = 0; reg < 4; ++reg) {
                int row = rbase + wave * 16 * MT + mt * 16 + quad * 4 + reg;
                if (row < M) {
#pragma unroll
                    for (int nt = 0; nt < NT; ++nt) {
                        float v = acc[mt][nt][reg] + bb[nt];
                        if (EPI == 1) v = fmaxf(v, 0.f);
                        if (OUTMODE == 1) {
                            int c = cbase + nt * 16 + l16;
                            if (c < 192) {
                                Chi[(size_t)row * 192 + c] = f2bf(v);
                            } else {
                                int cc = c - 192;
                                int idx = (cc < 192) ? (cc * 2) : ((cc - 192) * 2 + 1);
                                Clo[(size_t)row * 384 + idx] = f2bf(v);
                            }
                        } else {
                            size_t off = (size_t)row * ldc + cbase + nt * 16 + l16;
                            if (DUAL) {
                                unsigned short hi, lo;
                                split_bf16(v, hi, lo);
                                Chi[off] = hi; Clo[off] = lo;
                            } else {
                                Chi[off] = f2bf(v);
                            }
                        }
                    }
                }
            }
        }
    }
}

// ---------------- edge attention (round-6 layout, msgH-only output) -------------------
// no-max softmax (exact, shift-invariant; logits O(3)); 4-edge unroll.
__global__ __launch_bounds__(256)
void attn_kernel(const unsigned short* __restrict__ qB, const unsigned short* __restrict__ kvB,
                 const float* __restrict__ ea, const float* __restrict__ We_l,
                 const int2* __restrict__ csr2, const int* __restrict__ row_ptr,
                 unsigned short* __restrict__ msg_hi) {
    __shared__ float sWe[768];
    const int tid = threadIdx.x;
    for (int i = tid; i < 768; i += 256) sWe[i] = We_l[i];
    __syncthreads();

    const int lane = tid & 63;
    const int node = blockIdx.x * 4 + (tid >> 6);
    const int d0 = (lane >> 4) * 48 + (lane & 15) * 3;

    float W[4][3];
#pragma unroll
    for (int w = 0; w < 4; ++w) {
        W[w][0] = sWe[w * 192 + d0];
        W[w][1] = sWe[w * 192 + d0 + 1];
        W[w][2] = sWe[w * 192 + d0 + 2];
    }
    size_t qoff = (size_t)node * 192 + d0;
    float q0 = bf2f(qB[qoff]), q1 = bf2f(qB[qoff + 1]), q2 = bf2f(qB[qoff + 2]);
    float qe0 = q0 * W[0][0] + q1 * W[0][1] + q2 * W[0][2];
    float qe1 = q0 * W[1][0] + q1 * W[1][1] + q2 * W[1][2];
    float qe2 = q0 * W[2][0] + q1 * W[2][1] + q2 * W[2][2];
    float qe3 = q0 * W[3][0] + q1 * W[3][1] + q2 * W[3][2];
#pragma unroll
    for (int off = 1; off < 16; off <<= 1) {
        qe0 += __shfl_xor(qe0, off);
        qe1 += __shfl_xor(qe1, off);
        qe2 += __shfl_xor(qe2, off);
        qe3 += __shfl_xor(qe3, off);
    }

    const unsigned int* kv = (const unsigned int*)kvB;
    const float4* ea4 = (const float4*)ea;

    float den = 0.f;
    float v0 = 0.f, v1 = 0.f, v2 = 0.f;
    float wa0 = 0.f, wa1 = 0.f, wa2 = 0.f, wa3 = 0.f;
    const int beg = row_ptr[node], end = row_ptr[node + 1];
    int p = beg;
    for (; p + 3 < end; p += 4) {
        int2 seA = csr2[p], seB = csr2[p + 1], seC = csr2[p + 2], seD = csr2[p + 3];
        size_t bA = (size_t)seA.x * 192 + d0;
        size_t bB = (size_t)seB.x * 192 + d0;
        size_t bC = (size_t)seC.x * 192 + d0;
        size_t bD = (size_t)seD.x * 192 + d0;
        unsigned int uA0 = kv[bA], uA1 = kv[bA + 1], uA2 = kv[bA + 2];
        unsigned int uB0 = kv[bB], uB1 = kv[bB + 1], uB2 = kv[bB + 2];
        unsigned int uC0 = kv[bC], uC1 = kv[bC + 1], uC2 = kv[bC + 2];
        unsigned int uD0 = kv[bD], uD1 = kv[bD + 1], uD2 = kv[bD + 2];
        float4 wA = ea4[seA.y], wB = ea4[seB.y], wC = ea4[seC.y], wD = ea4[seD.y];
        float dA = q0 * bf2f((unsigned short)uA0) + q1 * bf2f((unsigned short)uA1) + q2 * bf2f((unsigned short)uA2);
        float dB = q0 * bf2f((unsigned short)uB0) + q1 * bf2f((unsigned short)uB1) + q2 * bf2f((unsigned short)uB2);
        float dC = q0 * bf2f((unsigned short)uC0) + q1 * bf2f((unsigned short)uC1) + q2 * bf2f((unsigned short)uC2);
        float dD = q0 * bf2f((unsigned short)uD0) + q1 * bf2f((unsigned short)uD1) + q2 * bf2f((unsigned short)uD2);
#pragma unroll
        for (int off = 1; off < 16; off <<= 1) {
            dA += __shfl_xor(dA, off);
            dB += __shfl_xor(dB, off);
            dC += __shfl_xor(dC, off);
            dD += __shfl_xor(dD, off);
        }
        float pA = __expf(dA + wA.x * qe0 + wA.y * qe1 + wA.z * qe2 + wA.w * qe3);
        float pB = __expf(dB + wB.x * qe0 + wB.y * qe1 + wB.z * qe2 + wB.w * qe3);
        float pC = __expf(dC + wC.x * qe0 + wC.y * qe1 + wC.z * qe2 + wC.w * qe3);
        float pD = __expf(dD + wD.x * qe0 + wD.y * qe1 + wD.z * qe2 + wD.w * qe3);
        den += pA + pB + pC + pD;
        v0 += pA * bf2f((unsigned short)(uA0 >> 16)) + pB * bf2f((unsigned short)(uB0 >> 16))
            + pC * bf2f((unsigned short)(uC0 >> 16)) + pD * bf2f((unsigned short)(uD0 >> 16));
        v1 += pA * bf2f((unsigned short)(uA1 >> 16)) + pB * bf2f((unsigned short)(uB1 >> 16))
            + pC * bf2f((unsigned short)(uC1 >> 16)) + pD * bf2f((unsigned short)(uD1 >> 16));
        v2 += pA * bf2f((unsigned short)(uA2 >> 16)) + pB * bf2f((unsigned short)(uB2 >> 16))
            + pC * bf2f((unsigned short)(uC2 >> 16)) + pD * bf2f((unsigned short)(uD2 >> 16));
        wa0 += pA * wA.x + pB * wB.x + pC * wC.x + pD * wD.x;
        wa1 += pA * wA.y + pB * wB.y + pC * wC.y + pD * wD.y;
        wa2 += pA * wA.z + pB * wB.z + pC * wC.z + pD * wD.z;
        wa3 += pA * wA.w + pB * wB.w + pC * wC.w + pD * wD.w;
    }
    for (; p < end; ++p) {
        int2 se = csr2[p];
        size_t b = (size_t)se.x * 192 + d0;
        unsigned int u0 = kv[b], u1 = kv[b + 1], u2 = kv[b + 2];
        float4 w = ea4[se.y];
        float d = q0 * bf2f((unsigned short)u0) + q1 * bf2f((unsigned short)u1)
                + q2 * bf2f((unsigned short)u2);
#pragma unroll
        for (int off = 1; off < 16; off <<= 1) d += __shfl_xor(d, off);
        float pe = __expf(d + w.x * qe0 + w.y * qe1 + w.z * qe2 + w.w * qe3);
        den += pe;
        v0 += pe * bf2f((unsigned short)(u0 >> 16));
        v1 += pe * bf2f((unsigned short)(u1 >> 16));
        v2 += pe * bf2f((unsigned short)(u2 >> 16));
        wa0 += pe * w.x;
        wa1 += pe * w.y;
        wa2 += pe * w.z;
        wa3 += pe * w.w;
    }
    float inv = 1.f / (den + 1e-16f);
    float m0 = (v0 + wa0 * W[0][0] + wa1 * W[1][0] + wa2 * W[2][0] + wa3 * W[3][0]) * inv;
    float m1 = (v1 + wa0 * W[0][1] + wa1 * W[1][1] + wa2 * W[2][1] + wa3 * W[3][1]) * inv;
    float m2 = (v2 + wa0 * W[0][2] + wa1 * W[1][2] + wa2 * W[2][2] + wa3 * W[3][2]) * inv;
    size_t ob = (size_t)node * 192 + d0;
    msg_hi[ob]     = f2bf(m0);
    msg_hi[ob + 1] = f2bf(m1);
    msg_hi[ob + 2] = f2bf(m2);
}

// ---------------- edge head: 128 edges/block (32/wave), swizzled sW LDS ---------------
__global__ __launch_bounds__(256, 2)
void edge_head_kernel(const unsigned short* __restrict__ hsd, const float* __restrict__ ea,
                      const int* __restrict__ src, const int* __restrict__ dst,
                      const float* __restrict__ W1e, const float* __restrict__ b1,
                      const unsigned short* __restrict__ W2hi,
                      const float* __restrict__ b2, const float* __restrict__ W3,
                      const float* __restrict__ b3, float* __restrict__ out) {
    __shared__ __align__(16) unsigned short sW[96 * 192];   // SBLK=24 blocks, swizzled
    __shared__ __align__(16) float sWe1[768];
    __shared__ __align__(16) float sB1[192];
    const int tid = threadIdx.x;
    const int wave = tid >> 6, lane = tid & 63;
    const int quad = lane >> 4, l16 = lane & 15;
    const int ebase = blockIdx.x * 128;

    for (int i = tid; i < 768; i += 256) sWe1[i] = W1e[i];
    if (tid < 192) sB1[tid] = b1[tid];
    for (int i = tid; i < 96 * 24; i += 256) {
        int n = i % 96, j = i / 96;
        *(uint4*)&sW[(n * 24 + (j ^ (n & 7))) * 8] = *(const uint4*)(W2hi + (size_t)n * 192 + j * 8);
    }

    const int e0 = ebase + wave * 32 + l16;       // group-0 edge
    const int e1 = e0 + 16;                       // group-1 edge
    const int s0 = src[e0], d0n = dst[e0];
    const int s1 = src[e1], d1n = dst[e1];
    const float4 eav0 = *(const float4*)(ea + (size_t)e0 * 4);
    const float4 eav1 = *(const float4*)(ea + (size_t)e1 * 4);
    const unsigned short* hs0_p = hsd + (size_t)s0 * 384 + quad * 8;
    const unsigned short* hd0_p = hsd + (size_t)d0n * 384 + 192 + quad * 8;
    const unsigned short* hs1_p = hsd + (size_t)s1 * 384 + quad * 8;
    const unsigned short* hd1_p = hsd + (size_t)d1n * 384 + 192 + quad * 8;

    floatx4 acc[2][6];
#pragma unroll
    for (int g = 0; g < 2; ++g)
#pragma unroll
        for (int nt = 0; nt < 6; ++nt) acc[g][nt] = (floatx4)0.0f;
    __syncthreads();

    ushort8 hs0_c = *(const ushort8*)hs0_p;
    ushort8 hd0_c = *(const ushort8*)hd0_p;
    ushort8 hs1_c = *(const ushort8*)hs1_p;
    ushort8 hd1_c = *(const ushort8*)hd1_p;
#pragma unroll
    for (int kc = 0; kc < 192; kc += 32) {
        ushort8 hs0_n = hs0_c, hd0_n = hd0_c, hs1_n = hs1_c, hd1_n = hd1_c;
        if (kc + 32 < 192) {
            hs0_n = *(const ushort8*)(hs0_p + kc + 32);
            hd0_n = *(const ushort8*)(hd0_p + kc + 32);
            hs1_n = *(const ushort8*)(hs1_p + kc + 32);
            hd1_n = *(const ushort8*)(hd1_p + kc + 32);
        }
        const int c0 = kc + quad * 8;
        float wb1[8], w0v[8], w1v[8], w2v[8], w3v[8];
        *(float4*)&wb1[0] = *(const float4*)&sB1[c0];
        *(float4*)&wb1[4] = *(const float4*)&sB1[c0 + 4];
        *(float4*)&w0v[0] = *(const float4*)&sWe1[c0];
        *(float4*)&w0v[4] = *(const float4*)&sWe1[c0 + 4];
        *(float4*)&w1v[0] = *(const float4*)&sWe1[192 + c0];
        *(float4*)&w1v[4] = *(const float4*)&sWe1[192 + c0 + 4];
        *(float4*)&w2v[0] = *(const float4*)&sWe1[384 + c0];
        *(float4*)&w2v[4] = *(const float4*)&sWe1[384 + c0 + 4];
        *(float4*)&w3v[0] = *(const float4*)&sWe1[576 + c0];
        *(float4*)&w3v[4] = *(const float4*)&sWe1[576 + c0 + 4];
        ushort8 ah0, ah1;
#pragma unroll
        for (int j = 0; j < 8; ++j) {
            float base = wb1[j];
            float ce0 = base + eav0.x * w0v[j] + eav0.y * w1v[j]
                      + eav0.z * w2v[j] + eav0.w * w3v[j];
            float ce1 = base + eav1.x * w0v[j] + eav1.y * w1v[j]
                      + eav1.z * w2v[j] + eav1.w * w3v[j];
            ah0[j] = f2bf(fmaxf(bf2f(hs0_c[j]) + bf2f(hd0_c[j]) + ce0, 0.f));
            ah1[j] = f2bf(fmaxf(bf2f(hs1_c[j]) + bf2f(hd1_c[j]) + ce1, 0.f));
        }
        short8 a0 = *(short8*)&ah0, a1 = *(short8*)&ah1;
        const int jbase = kc / 8;
#pragma unroll
        for (int nt = 0; nt < 6; ++nt) {
            int jj = (jbase + quad) ^ (l16 & 7);
            short8 bh = *(const short8*)&sW[((nt * 16 + l16) * 24 + jj) * 8];
            acc[0][nt] = mfma16(a0, bh, acc[0][nt]);
            acc[1][nt] = mfma16(a1, bh, acc[1][nt]);
        }
        hs0_c = hs0_n; hd0_c = hd0_n; hs1_c = hs1_n; hd1_c = hd1_n;
    }

    float w3[6], bb2[6];
#pragma unroll
    for (int nt = 0; nt < 6; ++nt) {
        int col = nt * 16 + l16;
        w3[nt] = W3[col];
        bb2[nt] = b2[col];
    }
    float b3v = b3[0];
#pragma unroll
    for (int g = 0; g < 2; ++g) {
#pragma unroll
        for (int reg = 0; reg < 4; ++reg) {
            float sacc = 0.f;
#pragma unroll
            for (int nt = 0; nt < 6; ++nt) {
                float z = fmaxf(acc[g][nt][reg] + bb2[nt], 0.f);
                sacc = fmaf(z, w3[nt], sacc);
            }
#pragma unroll
            for (int off = 1; off < 16; off <<= 1) sacc += __shfl_xor(sacc, off);
            if (l16 == 0) out[ebase + wave * 32 + g * 16 + quad * 4 + reg] = sacc + b3v;
        }
    }
}

extern "C" void kernel_launch(void* const* d_in, const int* in_sizes, int n_in,
                              void* d_out, int out_size, void* d_ws, size_t ws_size,
                              hipStream_t stream) {
    const float* x     = (const float*)d_in[0];
    const int*   eidx  = (const int*)d_in[1];
    const float* ea    = (const float*)d_in[2];
    const int*   batch = (const int*)d_in[3];
    const int*   gptr  = (const int*)d_in[4];
    const int*   tgid  = (const int*)d_in[5];
    const float* gp    = (const float*)d_in[6];
    const float* sp    = (const float*)d_in[7];
    const float* epp   = (const float*)d_in[8];
    const float* W_in  = (const float*)d_in[9];
    const float* b_in  = (const float*)d_in[10];
    const float* Wq    = (const float*)d_in[11];
    const float* Wk    = (const float*)d_in[12];
    const float* Wv    = (const float*)d_in[13];
    const float* We    = (const float*)d_in[14];
    const float* Wo    = (const float*)d_in[15];
    const float* bo    = (const float*)d_in[16];
    const float* ln1g  = (const float*)d_in[17];
    const float* ln1b  = (const float*)d_in[18];
    const float* Wf1   = (const float*)d_in[19];
    const float* bf1   = (const float*)d_in[20];
    const float* Wf2   = (const float*)d_in[21];
    const float* bf2   = (const float*)d_in[22];
    const float* ln2g  = (const float*)d_in[23];
    const float* ln2b  = (const float*)d_in[24];
    const float* We1   = (const float*)d_in[25];
    const float* be1   = (const float*)d_in[26];
    const float* We2   = (const float*)d_in[27];
    const float* be2   = (const float*)d_in[28];
    const float* We3   = (const float*)d_in[29];
    const float* be3   = (const float*)d_in[30];
    const int* src = eidx;
    const int* dst = eidx + N_EDGES;

    unsigned short* ub = (unsigned short*)d_ws;
    unsigned short* featH = ub;                  // 40000*32
    unsigned short* featL = ub + 1280000;
    unsigned short* hH    = ub + 2560000;        // 40000*192 each
    unsigned short* hL    = ub + 10240000;
    unsigned short* htH   = ub + 17920000;
    unsigned short* htL   = ub + 25600000;
    unsigned short* msgH  = ub + 33280000;
    unsigned short* rbuf  = ub + 48640000;       // 40000*768 region
    unsigned short* qB    = rbuf;                // 40000*192
    unsigned short* kvB   = rbuf + 7680000;      // 40000*384 interleaved k/v
    unsigned short* ffH   = rbuf;                // 40000*384 (after attn)
    unsigned short* hsdB  = rbuf;                // 40000*384
    unsigned short* wb    = ub + 79360000;       // WTOT
    int* ib   = (int*)(ub + 80343040);
    int* cnt  = ib;
    int* rowp = ib + 40000;
    int* curs = ib + 80004;
    int2* csr2 = (int2*)(ib + 120004);
    int* bsum  = ib + 920004;
    int* boffs = ib + 920044;

    hipMemsetAsync(cnt, 0, N_NODES * sizeof(int), stream);
    count_kernel<<<1563, 256, 0, stream>>>(dst, cnt, N_EDGES);
    scan1_kernel<<<40, 1024, 0, stream>>>(cnt, rowp, bsum, N_NODES);
    scan2_kernel<<<1, 64, 0, stream>>>(bsum, boffs, rowp, 40, N_NODES);
    scan3_kernel<<<40, 1024, 0, stream>>>(rowp, curs, boffs, N_NODES);
    scatter_kernel<<<1563, 256, 0, stream>>>(src, dst, curs, csr2, N_EDGES);
    feat_kernel<<<5000, 256, 0, stream>>>(x, batch, gptr, tgid, gp, sp, epp, featH, featL, N_NODES);
    prep_kernel<<<3840, 256, 0, stream>>>(W_in, Wq, Wk, Wv, Wo, Wf1, Wf2, We1, We2, wb);

    dim3 blk(256);
    // input projection: feat[40000, K=32 planes] @ W_in -> h planes (chunked, BM=64)
    mfma_gemm<0, 1, 96, 32, 2, 1><<<dim3(625, 2), blk, 0, stream>>>(featH, featL, N_NODES, 32,
        wb + WOFF_WIN, b_in, nullptr, nullptr, nullptr, nullptr, hH, hL, 192);

    for (int l = 0; l < 3; ++l) {
        const unsigned short* wq = wb + WOFF_QKV + l * 110592;
        // fused qkv, A-stationary BM=64: q -> qB, k/v -> kvB interleaved (single-term A)
        mfma_gemm_astat<0, 0, 96, 6, 1, 6, 1, 1><<<625, blk, 0, stream>>>(hH, hL, N_NODES,
            wq, nullptr, qB, kvB, 0);
        attn_kernel<<<10000, blk, 0, stream>>>(qB, kvB, ea, We + l * 768, csr2, rowp, msgH);
        // wo + residual + LN (msg single-plane -> TERMS=1); BM=64, KCH=64
        mfma_gemm<2, 1, 192, 64, 1, 1><<<dim3(625, 1), blk, 0, stream>>>(msgH, msgH, N_NODES, 192,
            wb + WOFF_WO + l * 36864, bo + l * 192, hH, hL, ln1g + l * 192, ln1b + l * 192,
            htH, htL, 192);
        // ff1: relu, single-plane output; BM=64
        mfma_gemm_astat<1, 0, 96, 4, 2, 6, 0, 1><<<625, blk, 0, stream>>>(htH, htL, N_NODES,
            wb + WOFF_WF1 + l * 73728, bf1 + l * 384, ffH, nullptr, 384);
        // ff2 + residual + LN (ff single-plane -> TERMS=1); BM=64, KCH=64
        mfma_gemm<2, 1, 192, 64, 1, 1><<<dim3(625, 1), blk, 0, stream>>>(ffH, ffH, N_NODES, 384,
            wb + WOFF_WF2 + l * 73728, bf2 + l * 192, htH, htL, ln2g + l * 192, ln2b + l * 192,
            hH, hL, 192);
    }

    // edge head pre-projections, A-stationary BM=64: [Hs|Hd] -> hsdB bf16 [N,384]
    mfma_gemm_astat<0, 0, 96, 4, 2, 6, 0, 1><<<625, blk, 0, stream>>>(hH, hL, N_NODES,
        wb + WOFF_HSD, nullptr, hsdB, nullptr, 384);
    edge_head_kernel<<<3125, blk, 0, stream>>>(hsdB, ea, src, dst,
        We1 + 384 * 192, be1, wb + WOFF_WE2, be2, We3, be3, (float*)d_out);
}

// Round 13
// 811.416 us; speedup vs baseline: 1.1316x; 1.0247x over previous
//
#include <hip/hip_runtime.h>
#include <hip/hip_bf16.h>
#include <math.h>

#define N_NODES 40000
#define N_EDGES 400000
#define GCLIP 511

using short8  = __attribute__((ext_vector_type(8))) short;
using ushort8 = __attribute__((ext_vector_type(8))) unsigned short;
using floatx4 = __attribute__((ext_vector_type(4))) float;

__device__ __forceinline__ void split_bf16(float v, unsigned short& hi, unsigned short& lo) {
    __hip_bfloat16 h = __float2bfloat16(v);
    float r = v - __bfloat162float(h);
    __hip_bfloat16 l = __float2bfloat16(r);
    hi = *(unsigned short*)&h;
    lo = *(unsigned short*)&l;
}
__device__ __forceinline__ unsigned short f2bf(float f) {
    __hip_bfloat16 h = __float2bfloat16(f);
    return *(unsigned short*)&h;
}
__device__ __forceinline__ float bf2f(unsigned short u) {
    __hip_bfloat16 h = *(__hip_bfloat16*)&u;
    return __bfloat162float(h);
}
__device__ __forceinline__ floatx4 mfma16(short8 a, short8 b, floatx4 c) {
    return __builtin_amdgcn_mfma_f32_16x16x32_bf16(a, b, c, 0, 0, 0);
}

// ---------------- CSR build ----------------
__global__ void count_kernel(const int* __restrict__ dst, int* __restrict__ cnt, int E) {
    int e = blockIdx.x * 256 + threadIdx.x;
    if (e < E) atomicAdd(&cnt[dst[e]], 1);
}

__global__ void scan1_kernel(const int* __restrict__ cnt, int* __restrict__ rowp,
                             int* __restrict__ bsum, int n) {
    __shared__ int wsum[16];
    __shared__ int woff[16];
    int tid = threadIdx.x, wave = tid >> 6, lane = tid & 63;
    int i = blockIdx.x * 1024 + tid;
    int v = (i < n) ? cnt[i] : 0;
    int x = v;
    for (int off = 1; off < 64; off <<= 1) {
        int t = __shfl_up(x, off);
        if (lane >= off) x += t;
    }
    if (lane == 63) wsum[wave] = x;
    __syncthreads();
    if (wave == 0 && lane < 16) {
        int s = wsum[lane];
        for (int off = 1; off < 16; off <<= 1) {
            int t = __shfl_up(s, off);
            if (lane >= off) s += t;
        }
        woff[lane] = s;
    }
    __syncthreads();
    int incl = x + ((wave == 0) ? 0 : woff[wave - 1]);
    if (i < n) rowp[i] = incl - v;
    if (tid == 1023) bsum[blockIdx.x] = incl;
}

__global__ void scan2_kernel(const int* __restrict__ bsum, int* __restrict__ boffs,
                             int* __restrict__ rowp, int nb, int n) {
    int lane = threadIdx.x;
    int v = (lane < nb) ? bsum[lane] : 0;
    int x = v;
    for (int off = 1; off < 64; off <<= 1) {
        int t = __shfl_up(x, off);
        if (lane >= off) x += t;
    }
    if (lane < nb) boffs[lane] = x - v;
    if (lane == nb - 1) rowp[n] = x;
}

__global__ void scan3_kernel(int* __restrict__ rowp, int* __restrict__ curs,
                             const int* __restrict__ boffs, int n) {
    int i = blockIdx.x * 1024 + threadIdx.x;
    if (i < n) {
        int v = rowp[i] + boffs[blockIdx.x];
        rowp[i] = v;
        curs[i] = v;
    }
}

__global__ void scatter_kernel(const int* __restrict__ src, const int* __restrict__ dst,
                               int* __restrict__ cursor, int2* __restrict__ csr2, int E) {
    int e = blockIdx.x * 256 + threadIdx.x;
    if (e < E) {
        int pos = atomicAdd(&cursor[dst[e]], 1);
        csr2[pos] = make_int2(src[e], e);
    }
}

// ---------------- feature build -> bf16 hi/lo planes [N][32] (cols 16..31 zero) -------
__global__ void feat_kernel(const float* __restrict__ x, const int* __restrict__ batch,
                            const int* __restrict__ gptr, const int* __restrict__ tgid,
                            const float* __restrict__ gp, const float* __restrict__ sp,
                            const float* __restrict__ ep,
                            unsigned short* __restrict__ fhi, unsigned short* __restrict__ flo,
                            int n) {
    int idx = blockIdx.x * 256 + threadIdx.x;
    if (idx >= n * 32) return;
    int node = idx >> 5, c = idx & 31;
    float v = 0.f;
    if (c < 4) {
        v = x[node * 4 + c];
    } else if (c < 7) {
        int gid = gptr[batch[node]] + tgid[node];
        gid = min(max(gid, 0), GCLIP);
        v = gp[gid * 3 + (c - 4)];
    } else if (c < 10) {
        v = sp[node * 3 + (c - 7)];
    } else if (c < 16) {
        int gid = gptr[batch[node]] + tgid[node];
        gid = min(max(gid, 0), GCLIP);
        v = ep[gid * 6 + (c - 10)];
    }
    unsigned short hi, lo;
    split_bf16(v, hi, lo);
    fhi[idx] = hi;
    flo[idx] = lo;
}

// ---------------- weight prep: transpose to [Nrows][Ka] bf16 (hi only) ----------------
#define WOFF_WIN 0
#define WOFF_QKV 6144
#define WOFF_WO  337920
#define WOFF_WF1 448512
#define WOFF_WF2 669696
#define WOFF_HSD 890880
#define WOFF_WE2 964608
#define WTOT     983040

__global__ void prep_kernel(const float* __restrict__ W_in, const float* __restrict__ Wq,
                            const float* __restrict__ Wk, const float* __restrict__ Wv,
                            const float* __restrict__ Wo, const float* __restrict__ Wf1,
                            const float* __restrict__ Wf2, const float* __restrict__ We1,
                            const float* __restrict__ We2, unsigned short* __restrict__ wb) {
    int idx = blockIdx.x * 256 + threadIdx.x;
    if (idx >= WTOT) return;
    float val;
    if (idx < WOFF_QKV) {                       // W_in^T [192][32], K=16 padded
        int n = idx / 32, k = idx % 32;
        val = (k < 16) ? W_in[k * 192 + n] : 0.f;
    } else if (idx < WOFF_WO) {                 // Wqkv^T [576][192] x3; q rows pre-scaled
        int r = idx - WOFF_QKV; int l = r / 110592; r %= 110592;
        int n = r / 192, k = r % 192;
        const float* s = (n < 192) ? Wq : (n < 384 ? Wk : Wv);
        val = s[l * 36864 + k * 192 + (n % 192)];
        if (n < 192) val *= 0.14433756729740643f;   // 1/sqrt(48) folded into Wq
    } else if (idx < WOFF_WF1) {                // Wo^T [192][192] x3
        int r = idx - WOFF_WO; int l = r / 36864; r %= 36864;
        int n = r / 192, k = r % 192;
        val = Wo[l * 36864 + k * 192 + n];
    } else if (idx < WOFF_WF2) {                // Wf1^T [384][192] x3
        int r = idx - WOFF_WF1; int l = r / 73728; r %= 73728;
        int n = r / 192, k = r % 192;
        val = Wf1[l * 73728 + k * 384 + n];
    } else if (idx < WOFF_HSD) {                // Wf2^T [192][384] x3
        int r = idx - WOFF_WF2; int l = r / 73728; r %= 73728;
        int n = r / 384, k = r % 384;
        val = Wf2[l * 73728 + k * 192 + n];
    } else if (idx < WOFF_WE2) {                // [Hs|Hd]^T [384][192]
        int r = idx - WOFF_HSD;
        int n = r / 192, k = r % 192;
        val = (n < 192) ? We1[k * 192 + n] : We1[(192 + k) * 192 + (n - 192)];
    } else {                                    // We2^T [96][192]
        int r = idx - WOFF_WE2;
        int n = r / 192, k = r % 192;
        val = We2[k * 96 + n];
    }
    wb[idx] = f2bf(val);
}

// LDS tile layout: row n holds k-block j (8 ushorts) at slot (j ^ (n&7)); row stride
// SBLK % 8 == 0 blocks -> stride 0 mod 32 dwords -> conflict-free fragment reads.

// ---------------- chunked MFMA GEMM (input proj / wo / ff2) ---------------------------
// BM = 64*MT (4 waves x 16*MT rows). DUAL gates lo-plane on resid read AND C write.
// NOTE: residual stream (h, ht) must stay DUAL=1 — bf16-rounding the stream compounds
// through 3 layers to ~0.02 absmax (measured r12). Branch quantities (msg, ff) are safe
// single-plane (measured r11: no absmax change).
template <int EPI, int DUAL, int BN, int KCH, int TERMS, int MT>
__global__ __launch_bounds__(256, 4)
void mfma_gemm(const unsigned short* __restrict__ Ahi, const unsigned short* __restrict__ Alo,
               int M, int Ka,
               const unsigned short* __restrict__ B, const float* __restrict__ bias,
               const unsigned short* __restrict__ Rhi, const unsigned short* __restrict__ Rlo,
               const float* __restrict__ lng, const float* __restrict__ lnb,
               unsigned short* __restrict__ Chi, unsigned short* __restrict__ Clo, int ldc) {
    constexpr int NT = BN / 16;
    constexpr int JB = KCH / 8;
    constexpr int SBLK = ((JB + 7) / 8) * 8;
    __shared__ __align__(16) unsigned short sB[BN * SBLK * 8];
    const int tid = threadIdx.x;
    const int wave = tid >> 6, lane = tid & 63;
    const int quad = lane >> 4, l16 = lane & 15;
    const int rbase = blockIdx.x * 64 * MT;
    const int cbase = blockIdx.y * BN;

    floatx4 acc[MT][NT];
#pragma unroll
    for (int mt = 0; mt < MT; ++mt)
#pragma unroll
        for (int nt = 0; nt < NT; ++nt) acc[mt][nt] = (floatx4)0.0f;

    const unsigned short* pah[MT];
    const unsigned short* pal[MT];
#pragma unroll
    for (int mt = 0; mt < MT; ++mt) {
        int r = min(rbase + wave * 16 * MT + mt * 16 + l16, M - 1);
        pah[mt] = Ahi + (size_t)r * Ka + quad * 8;
        pal[mt] = Alo + (size_t)r * Ka + quad * 8;
    }

    for (int kb = 0; kb < Ka; kb += KCH) {
        if (kb) __syncthreads();
        for (int i = tid; i < BN * JB; i += 256) {
            int n = i % BN, j = i / BN;
            *(uint4*)&sB[(n * SBLK + (j ^ (n & 7))) * 8] =
                *(const uint4*)(B + (size_t)(cbase + n) * Ka + kb + j * 8);
        }
        __syncthreads();
        short8 ch[MT], cl[MT];
#pragma unroll
        for (int mt = 0; mt < MT; ++mt) {
            ch[mt] = *(const short8*)(pah[mt] + kb);
            if (TERMS == 2) cl[mt] = *(const short8*)(pal[mt] + kb);
        }
#pragma unroll
        for (int kc = 0; kc < KCH; kc += 32) {
            short8 nh[MT], nl[MT];
#pragma unroll
            for (int mt = 0; mt < MT; ++mt) { nh[mt] = ch[mt]; nl[mt] = ch[mt]; }
            if (kc + 32 < KCH) {
#pragma unroll
                for (int mt = 0; mt < MT; ++mt) {
                    nh[mt] = *(const short8*)(pah[mt] + kb + kc + 32);
                    if (TERMS == 2) nl[mt] = *(const short8*)(pal[mt] + kb + kc + 32);
                }
            }
            const int jbase = kc / 8;
#pragma unroll
            for (int nt = 0; nt < NT; ++nt) {
                int jj = (jbase + quad) ^ (l16 & 7);
                short8 b = *(const short8*)&sB[((nt * 16 + l16) * SBLK + jj) * 8];
#pragma unroll
                for (int mt = 0; mt < MT; ++mt) {
                    acc[mt][nt] = mfma16(ch[mt], b, acc[mt][nt]);
                    if (TERMS == 2) acc[mt][nt] = mfma16(cl[mt], b, acc[mt][nt]);
                }
            }
#pragma unroll
            for (int mt = 0; mt < MT; ++mt) {
                ch[mt] = nh[mt];
                if (TERMS == 2) cl[mt] = nl[mt];
            }
        }
    }

    float bb[NT], gg[NT], be[NT];
#pragma unroll
    for (int nt = 0; nt < NT; ++nt) {
        int colg = cbase + nt * 16 + l16;
        bb[nt] = bias ? bias[colg] : 0.f;
        if (EPI == 2) { gg[nt] = lng[colg]; be[nt] = lnb[colg]; }
    }
#pragma unroll
    for (int mt = 0; mt < MT; ++mt) {
#pragma unroll
        for (int reg = 0; reg < 4; ++reg) {
            int row = rbase + wave * 16 * MT + mt * 16 + quad * 4 + reg;
            if (EPI == 2) {
                int rr = min(row, M - 1);
                float v[NT], s = 0.f, q = 0.f;
#pragma unroll
                for (int nt = 0; nt < NT; ++nt) {
                    size_t off = (size_t)rr * 192 + nt * 16 + l16;
                    float resid = bf2f(Rhi[off]);
                    if (DUAL) resid += bf2f(Rlo[off]);
                    v[nt] = acc[mt][nt][reg] + bb[nt] + resid;
                    s += v[nt]; q += v[nt] * v[nt];
                }
#pragma unroll
                for (int off = 1; off < 16; off <<= 1) {
                    s += __shfl_xor(s, off);
                    q += __shfl_xor(q, off);
                }
                float mean = s * (1.f / 192.f);
                float var = q * (1.f / 192.f) - mean * mean;
                float rs = rsqrtf(var + 1e-5f);
                if (row < M) {
#pragma unroll
                    for (int nt = 0; nt < NT; ++nt) {
                        float r = (v[nt] - mean) * rs * gg[nt] + be[nt];
                        size_t off = (size_t)row * 192 + nt * 16 + l16;
                        if (DUAL) {
                            unsigned short hi, lo;
                            split_bf16(r, hi, lo);
                            Chi[off] = hi; Clo[off] = lo;
                        } else {
                            Chi[off] = f2bf(r);
                        }
                    }
                }
            } else if (row < M) {
#pragma unroll
                for (int nt = 0; nt < NT; ++nt) {
                    float v = acc[mt][nt][reg] + bb[nt];
                    if (EPI == 1) v = fmaxf(v, 0.f);
                    size_t off = (size_t)row * ldc + cbase + nt * 16 + l16;
                    if (DUAL) {
                        unsigned short hi, lo;
                        split_bf16(v, hi, lo);
                        Chi[off] = hi; Clo[off] = lo;
                    } else {
                        Chi[off] = f2bf(v);
                    }
                }
            }
        }
    }
}

// ---------------- A-stationary MFMA GEMM (qkv / ff1 / hsd), BM = 64*MT ----------------
template <int EPI, int DUAL, int BN, int NTILES, int TERMS, int KF, int OUTMODE, int MT>
__global__ __launch_bounds__(256, 4)
void mfma_gemm_astat(const unsigned short* __restrict__ Ahi, const unsigned short* __restrict__ Alo,
                     int M, const unsigned short* __restrict__ B, const float* __restrict__ bias,
                     unsigned short* __restrict__ Chi, unsigned short* __restrict__ Clo, int ldc) {
    constexpr int NT = BN / 16;
    constexpr int Ka = KF * 32;
    constexpr int SBLK = KF * 4;
    __shared__ __align__(16) unsigned short sB[BN * SBLK * 8];
    const int tid = threadIdx.x;
    const int wave = tid >> 6, lane = tid & 63;
    const int quad = lane >> 4, l16 = lane & 15;
    const int rbase = blockIdx.x * 64 * MT;

    short8 afh[MT][KF], afl[MT][KF];
#pragma unroll
    for (int mt = 0; mt < MT; ++mt) {
        int r = min(rbase + wave * 16 * MT + mt * 16 + l16, M - 1);
        const unsigned short* ph = Ahi + (size_t)r * Ka + quad * 8;
        const unsigned short* pl = Alo + (size_t)r * Ka + quad * 8;
#pragma unroll
        for (int kf = 0; kf < KF; ++kf) {
            afh[mt][kf] = *(const short8*)(ph + kf * 32);
            if (TERMS == 2) afl[mt][kf] = *(const short8*)(pl + kf * 32);
        }
    }

    for (int t = 0; t < NTILES; ++t) {
        const int cbase = t * BN;
        if (t) __syncthreads();
        for (int i = tid; i < BN * KF * 4; i += 256) {
            int n = i % BN, j = i / BN;
            *(uint4*)&sB[(n * SBLK + (j ^ (n & 7))) * 8] =
                *(const uint4*)(B + (size_t)(cbase + n) * Ka + j * 8);
        }
        __syncthreads();

        floatx4 acc[MT][NT];
#pragma unroll
        for (int mt = 0; mt < MT; ++mt)
#pragma unroll
            for (int nt = 0; nt < NT; ++nt) acc[mt][nt] = (floatx4)0.0f;

#pragma unroll
        for (int kf = 0; kf < KF; ++kf) {
#pragma unroll
            for (int nt = 0; nt < NT; ++nt) {
                int jj = (kf * 4 + quad) ^ (l16 & 7);
                short8 b = *(const short8*)&sB[((nt * 16 + l16) * SBLK + jj) * 8];
#pragma unroll
                for (int mt = 0; mt < MT; ++mt) {
                    acc[mt][nt] = mfma16(afh[mt][kf], b, acc[mt][nt]);
                    if (TERMS == 2) acc[mt][nt] = mfma16(afl[mt][kf], b, acc[mt][nt]);
                }
            }
        }

        float bb[NT];
#pragma unroll
        for (int nt = 0; nt < NT; ++nt) bb[nt] = bias ? bias[cbase + nt * 16 + l16] : 0.f;
#pragma unroll
        for (int mt = 0; mt < MT; ++mt) {
#pragma unroll
            for (int reg = 0; reg < 4; ++reg) {
                int row = rbase + wave * 16 * MT + mt * 16 + quad * 4 + reg;
                if (row < M) {
#pragma unroll
                    for (int nt = 0; nt < NT; ++nt) {
                        float v = acc[mt][nt][reg] + bb[nt];
                        if (EPI == 1) v = fmaxf(v, 0.f);
                        if (OUTMODE == 1) {
                            int c = cbase + nt * 16 + l16;
                            if (c < 192) {
                                Chi[(size_t)row * 192 + c] = f2bf(v);
                            } else {
                                int cc = c - 192;
                                int idx = (cc < 192) ? (cc * 2) : ((cc - 192) * 2 + 1);
                                Clo[(size_t)row * 384 + idx] = f2bf(v);
                            }
                        } else {
                            size_t off = (size_t)row * ldc + cbase + nt * 16 + l16;
                            if (DUAL) {
                                unsigned short hi, lo;
                                split_bf16(v, hi, lo);
                                Chi[off] = hi; Clo[off] = lo;
                            } else {
                                Chi[off] = f2bf(v);
                            }
                        }
                    }
                }
            }
        }
    }
}

// ---------------- edge attention (round-6 layout, msgH-only output) -------------------
// no-max softmax (exact, shift-invariant; logits O(3)); 4-edge unroll.
__global__ __launch_bounds__(256)
void attn_kernel(const unsigned short* __restrict__ qB, const unsigned short* __restrict__ kvB,
                 const float* __restrict__ ea, const float* __restrict__ We_l,
                 const int2* __restrict__ csr2, const int* __restrict__ row_ptr,
                 unsigned short* __restrict__ msg_hi) {
    __shared__ float sWe[768];
    const int tid = threadIdx.x;
    for (int i = tid; i < 768; i += 256) sWe[i] = We_l[i];
    __syncthreads();

    const int lane = tid & 63;
    const int node = blockIdx.x * 4 + (tid >> 6);
    const int d0 = (lane >> 4) * 48 + (lane & 15) * 3;

    float W[4][3];
#pragma unroll
    for (int w = 0; w < 4; ++w) {
        W[w][0] = sWe[w * 192 + d0];
        W[w][1] = sWe[w * 192 + d0 + 1];
        W[w][2] = sWe[w * 192 + d0 + 2];
    }
    size_t qoff = (size_t)node * 192 + d0;
    float q0 = bf2f(qB[qoff]), q1 = bf2f(qB[qoff + 1]), q2 = bf2f(qB[qoff + 2]);
    float qe0 = q0 * W[0][0] + q1 * W[0][1] + q2 * W[0][2];
    float qe1 = q0 * W[1][0] + q1 * W[1][1] + q2 * W[1][2];
    float qe2 = q0 * W[2][0] + q1 * W[2][1] + q2 * W[2][2];
    float qe3 = q0 * W[3][0] + q1 * W[3][1] + q2 * W[3][2];
#pragma unroll
    for (int off = 1; off < 16; off <<= 1) {
        qe0 += __shfl_xor(qe0, off);
        qe1 += __shfl_xor(qe1, off);
        qe2 += __shfl_xor(qe2, off);
        qe3 += __shfl_xor(qe3, off);
    }

    const unsigned int* kv = (const unsigned int*)kvB;
    const float4* ea4 = (const float4*)ea;

    float den = 0.f;
    float v0 = 0.f, v1 = 0.f, v2 = 0.f;
    float wa0 = 0.f, wa1 = 0.f, wa2 = 0.f, wa3 = 0.f;
    const int beg = row_ptr[node], end = row_ptr[node + 1];
    int p = beg;
    for (; p + 3 < end; p += 4) {
        int2 seA = csr2[p], seB = csr2[p + 1], seC = csr2[p + 2], seD = csr2[p + 3];
        size_t bA = (size_t)seA.x * 192 + d0;
        size_t bB = (size_t)seB.x * 192 + d0;
        size_t bC = (size_t)seC.x * 192 + d0;
        size_t bD = (size_t)seD.x * 192 + d0;
        unsigned int uA0 = kv[bA], uA1 = kv[bA + 1], uA2 = kv[bA + 2];
        unsigned int uB0 = kv[bB], uB1 = kv[bB + 1], uB2 = kv[bB + 2];
        unsigned int uC0 = kv[bC], uC1 = kv[bC + 1], uC2 = kv[bC + 2];
        unsigned int uD0 = kv[bD], uD1 = kv[bD + 1], uD2 = kv[bD + 2];
        float4 wA = ea4[seA.y], wB = ea4[seB.y], wC = ea4[seC.y], wD = ea4[seD.y];
        float dA = q0 * bf2f((unsigned short)uA0) + q1 * bf2f((unsigned short)uA1) + q2 * bf2f((unsigned short)uA2);
        float dB = q0 * bf2f((unsigned short)uB0) + q1 * bf2f((unsigned short)uB1) + q2 * bf2f((unsigned short)uB2);
        float dC = q0 * bf2f((unsigned short)uC0) + q1 * bf2f((unsigned short)uC1) + q2 * bf2f((unsigned short)uC2);
        float dD = q0 * bf2f((unsigned short)uD0) + q1 * bf2f((unsigned short)uD1) + q2 * bf2f((unsigned short)uD2);
#pragma unroll
        for (int off = 1; off < 16; off <<= 1) {
            dA += __shfl_xor(dA, off);
            dB += __shfl_xor(dB, off);
            dC += __shfl_xor(dC, off);
            dD += __shfl_xor(dD, off);
        }
        float pA = __expf(dA + wA.x * qe0 + wA.y * qe1 + wA.z * qe2 + wA.w * qe3);
        float pB = __expf(dB + wB.x * qe0 + wB.y * qe1 + wB.z * qe2 + wB.w * qe3);
        float pC = __expf(dC + wC.x * qe0 + wC.y * qe1 + wC.z * qe2 + wC.w * qe3);
        float pD = __expf(dD + wD.x * qe0 + wD.y * qe1 + wD.z * qe2 + wD.w * qe3);
        den += pA + pB + pC + pD;
        v0 += pA * bf2f((unsigned short)(uA0 >> 16)) + pB * bf2f((unsigned short)(uB0 >> 16))
            + pC * bf2f((unsigned short)(uC0 >> 16)) + pD * bf2f((unsigned short)(uD0 >> 16));
        v1 += pA * bf2f((unsigned short)(uA1 >> 16)) + pB * bf2f((unsigned short)(uB1 >> 16))
            + pC * bf2f((unsigned short)(uC1 >> 16)) + pD * bf2f((unsigned short)(uD1 >> 16));
        v2 += pA * bf2f((unsigned short)(uA2 >> 16)) + pB * bf2f((unsigned short)(uB2 >> 16))
            + pC * bf2f((unsigned short)(uC2 >> 16)) + pD * bf2f((unsigned short)(uD2 >> 16));
        wa0 += pA * wA.x + pB * wB.x + pC * wC.x + pD * wD.x;
        wa1 += pA * wA.y + pB * wB.y + pC * wC.y + pD * wD.y;
        wa2 += pA * wA.z + pB * wB.z + pC * wC.z + pD * wD.z;
        wa3 += pA * wA.w + pB * wB.w + pC * wC.w + pD * wD.w;
    }
    for (; p < end; ++p) {
        int2 se = csr2[p];
        size_t b = (size_t)se.x * 192 + d0;
        unsigned int u0 = kv[b], u1 = kv[b + 1], u2 = kv[b + 2];
        float4 w = ea4[se.y];
        float d = q0 * bf2f((unsigned short)u0) + q1 * bf2f((unsigned short)u1)
                + q2 * bf2f((unsigned short)u2);
#pragma unroll
        for (int off = 1; off < 16; off <<= 1) d += __shfl_xor(d, off);
        float pe = __expf(d + w.x * qe0 + w.y * qe1 + w.z * qe2 + w.w * qe3);
        den += pe;
        v0 += pe * bf2f((unsigned short)(u0 >> 16));
        v1 += pe * bf2f((unsigned short)(u1 >> 16));
        v2 += pe * bf2f((unsigned short)(u2 >> 16));
        wa0 += pe * w.x;
        wa1 += pe * w.y;
        wa2 += pe * w.z;
        wa3 += pe * w.w;
    }
    float inv = 1.f / (den + 1e-16f);
    float m0 = (v0 + wa0 * W[0][0] + wa1 * W[1][0] + wa2 * W[2][0] + wa3 * W[3][0]) * inv;
    float m1 = (v1 + wa0 * W[0][1] + wa1 * W[1][1] + wa2 * W[2][1] + wa3 * W[3][1]) * inv;
    float m2 = (v2 + wa0 * W[0][2] + wa1 * W[1][2] + wa2 * W[2][2] + wa3 * W[3][2]) * inv;
    size_t ob = (size_t)node * 192 + d0;
    msg_hi[ob]     = f2bf(m0);
    msg_hi[ob + 1] = f2bf(m1);
    msg_hi[ob + 2] = f2bf(m2);
}

// ---------------- edge head: 128 edges/block (32/wave), swizzled sW LDS ---------------
__global__ __launch_bounds__(256, 2)
void edge_head_kernel(const unsigned short* __restrict__ hsd, const float* __restrict__ ea,
                      const int* __restrict__ src, const int* __restrict__ dst,
                      const float* __restrict__ W1e, const float* __restrict__ b1,
                      const unsigned short* __restrict__ W2hi,
                      const float* __restrict__ b2, const float* __restrict__ W3,
                      const float* __restrict__ b3, float* __restrict__ out) {
    __shared__ __align__(16) unsigned short sW[96 * 192];   // SBLK=24 blocks, swizzled
    __shared__ __align__(16) float sWe1[768];
    __shared__ __align__(16) float sB1[192];
    const int tid = threadIdx.x;
    const int wave = tid >> 6, lane = tid & 63;
    const int quad = lane >> 4, l16 = lane & 15;
    const int ebase = blockIdx.x * 128;

    for (int i = tid; i < 768; i += 256) sWe1[i] = W1e[i];
    if (tid < 192) sB1[tid] = b1[tid];
    for (int i = tid; i < 96 * 24; i += 256) {
        int n = i % 96, j = i / 96;
        *(uint4*)&sW[(n * 24 + (j ^ (n & 7))) * 8] = *(const uint4*)(W2hi + (size_t)n * 192 + j * 8);
    }

    const int e0 = ebase + wave * 32 + l16;       // group-0 edge
    const int e1 = e0 + 16;                       // group-1 edge
    const int s0 = src[e0], d0n = dst[e0];
    const int s1 = src[e1], d1n = dst[e1];
    const float4 eav0 = *(const float4*)(ea + (size_t)e0 * 4);
    const float4 eav1 = *(const float4*)(ea + (size_t)e1 * 4);
    const unsigned short* hs0_p = hsd + (size_t)s0 * 384 + quad * 8;
    const unsigned short* hd0_p = hsd + (size_t)d0n * 384 + 192 + quad * 8;
    const unsigned short* hs1_p = hsd + (size_t)s1 * 384 + quad * 8;
    const unsigned short* hd1_p = hsd + (size_t)d1n * 384 + 192 + quad * 8;

    floatx4 acc[2][6];
#pragma unroll
    for (int g = 0; g < 2; ++g)
#pragma unroll
        for (int nt = 0; nt < 6; ++nt) acc[g][nt] = (floatx4)0.0f;
    __syncthreads();

    ushort8 hs0_c = *(const ushort8*)hs0_p;
    ushort8 hd0_c = *(const ushort8*)hd0_p;
    ushort8 hs1_c = *(const ushort8*)hs1_p;
    ushort8 hd1_c = *(const ushort8*)hd1_p;
#pragma unroll
    for (int kc = 0; kc < 192; kc += 32) {
        ushort8 hs0_n = hs0_c, hd0_n = hd0_c, hs1_n = hs1_c, hd1_n = hd1_c;
        if (kc + 32 < 192) {
            hs0_n = *(const ushort8*)(hs0_p + kc + 32);
            hd0_n = *(const ushort8*)(hd0_p + kc + 32);
            hs1_n = *(const ushort8*)(hs1_p + kc + 32);
            hd1_n = *(const ushort8*)(hd1_p + kc + 32);
        }
        const int c0 = kc + quad * 8;
        float wb1[8], w0v[8], w1v[8], w2v[8], w3v[8];
        *(float4*)&wb1[0] = *(const float4*)&sB1[c0];
        *(float4*)&wb1[4] = *(const float4*)&sB1[c0 + 4];
        *(float4*)&w0v[0] = *(const float4*)&sWe1[c0];
        *(float4*)&w0v[4] = *(const float4*)&sWe1[c0 + 4];
        *(float4*)&w1v[0] = *(const float4*)&sWe1[192 + c0];
        *(float4*)&w1v[4] = *(const float4*)&sWe1[192 + c0 + 4];
        *(float4*)&w2v[0] = *(const float4*)&sWe1[384 + c0];
        *(float4*)&w2v[4] = *(const float4*)&sWe1[384 + c0 + 4];
        *(float4*)&w3v[0] = *(const float4*)&sWe1[576 + c0];
        *(float4*)&w3v[4] = *(const float4*)&sWe1[576 + c0 + 4];
        ushort8 ah0, ah1;
#pragma unroll
        for (int j = 0; j < 8; ++j) {
            float base = wb1[j];
            float ce0 = base + eav0.x * w0v[j] + eav0.y * w1v[j]
                      + eav0.z * w2v[j] + eav0.w * w3v[j];
            float ce1 = base + eav1.x * w0v[j] + eav1.y * w1v[j]
                      + eav1.z * w2v[j] + eav1.w * w3v[j];
            ah0[j] = f2bf(fmaxf(bf2f(hs0_c[j]) + bf2f(hd0_c[j]) + ce0, 0.f));
            ah1[j] = f2bf(fmaxf(bf2f(hs1_c[j]) + bf2f(hd1_c[j]) + ce1, 0.f));
        }
        short8 a0 = *(short8*)&ah0, a1 = *(short8*)&ah1;
        const int jbase = kc / 8;
#pragma unroll
        for (int nt = 0; nt < 6; ++nt) {
            int jj = (jbase + quad) ^ (l16 & 7);
            short8 bh = *(const short8*)&sW[((nt * 16 + l16) * 24 + jj) * 8];
            acc[0][nt] = mfma16(a0, bh, acc[0][nt]);
            acc[1][nt] = mfma16(a1, bh, acc[1][nt]);
        }
        hs0_c = hs0_n; hd0_c = hd0_n; hs1_c = hs1_n; hd1_c = hd1_n;
    }

    float w3[6], bb2[6];
#pragma unroll
    for (int nt = 0; nt < 6; ++nt) {
        int col = nt * 16 + l16;
        w3[nt] = W3[col];
        bb2[nt] = b2[col];
    }
    float b3v = b3[0];
#pragma unroll
    for (int g = 0; g < 2; ++g) {
#pragma unroll
        for (int reg = 0; reg < 4; ++reg) {
            float sacc = 0.f;
#pragma unroll
            for (int nt = 0; nt < 6; ++nt) {
                float z = fmaxf(acc[g][nt][reg] + bb2[nt], 0.f);
                sacc = fmaf(z, w3[nt], sacc);
            }
#pragma unroll
            for (int off = 1; off < 16; off <<= 1) sacc += __shfl_xor(sacc, off);
            if (l16 == 0) out[ebase + wave * 32 + g * 16 + quad * 4 + reg] = sacc + b3v;
        }
    }
}

extern "C" void kernel_launch(void* const* d_in, const int* in_sizes, int n_in,
                              void* d_out, int out_size, void* d_ws, size_t ws_size,
                              hipStream_t stream) {
    const float* x     = (const float*)d_in[0];
    const int*   eidx  = (const int*)d_in[1];
    const float* ea    = (const float*)d_in[2];
    const int*   batch = (const int*)d_in[3];
    const int*   gptr  = (const int*)d_in[4];
    const int*   tgid  = (const int*)d_in[5];
    const float* gp    = (const float*)d_in[6];
    const float* sp    = (const float*)d_in[7];
    const float* epp   = (const float*)d_in[8];
    const float* W_in  = (const float*)d_in[9];
    const float* b_in  = (const float*)d_in[10];
    const float* Wq    = (const float*)d_in[11];
    const float* Wk    = (const float*)d_in[12];
    const float* Wv    = (const float*)d_in[13];
    const float* We    = (const float*)d_in[14];
    const float* Wo    = (const float*)d_in[15];
    const float* bo    = (const float*)d_in[16];
    const float* ln1g  = (const float*)d_in[17];
    const float* ln1b  = (const float*)d_in[18];
    const float* Wf1   = (const float*)d_in[19];
    const float* bf1   = (const float*)d_in[20];
    const float* Wf2   = (const float*)d_in[21];
    const float* bf2   = (const float*)d_in[22];
    const float* ln2g  = (const float*)d_in[23];
    const float* ln2b  = (const float*)d_in[24];
    const float* We1   = (const float*)d_in[25];
    const float* be1   = (const float*)d_in[26];
    const float* We2   = (const float*)d_in[27];
    const float* be2   = (const float*)d_in[28];
    const float* We3   = (const float*)d_in[29];
    const float* be3   = (const float*)d_in[30];
    const int* src = eidx;
    const int* dst = eidx + N_EDGES;

    unsigned short* ub = (unsigned short*)d_ws;
    unsigned short* featH = ub;                  // 40000*32
    unsigned short* featL = ub + 1280000;
    unsigned short* hH    = ub + 2560000;        // 40000*192 each; h/ht dual-plane stream
    unsigned short* hL    = ub + 10240000;
    unsigned short* htH   = ub + 17920000;
    unsigned short* htL   = ub + 25600000;
    unsigned short* msgH  = ub + 33280000;
    unsigned short* rbuf  = ub + 48640000;       // 40000*768 region
    unsigned short* qB    = rbuf;                // 40000*192
    unsigned short* kvB   = rbuf + 7680000;      // 40000*384 interleaved k/v
    unsigned short* ffH   = rbuf;                // 40000*384 (after attn)
    unsigned short* hsdB  = rbuf;                // 40000*384
    unsigned short* wb    = ub + 79360000;       // WTOT
    int* ib   = (int*)(ub + 80343040);
    int* cnt  = ib;
    int* rowp = ib + 40000;
    int* curs = ib + 80004;
    int2* csr2 = (int2*)(ib + 120004);
    int* bsum  = ib + 920004;
    int* boffs = ib + 920044;

    hipMemsetAsync(cnt, 0, N_NODES * sizeof(int), stream);
    count_kernel<<<1563, 256, 0, stream>>>(dst, cnt, N_EDGES);
    scan1_kernel<<<40, 1024, 0, stream>>>(cnt, rowp, bsum, N_NODES);
    scan2_kernel<<<1, 64, 0, stream>>>(bsum, boffs, rowp, 40, N_NODES);
    scan3_kernel<<<40, 1024, 0, stream>>>(rowp, curs, boffs, N_NODES);
    scatter_kernel<<<1563, 256, 0, stream>>>(src, dst, curs, csr2, N_EDGES);
    feat_kernel<<<5000, 256, 0, stream>>>(x, batch, gptr, tgid, gp, sp, epp, featH, featL, N_NODES);
    prep_kernel<<<3840, 256, 0, stream>>>(W_in, Wq, Wk, Wv, Wo, Wf1, Wf2, We1, We2, wb);

    dim3 blk(256);
    // input projection: feat @ W_in -> h planes (DUAL output), BN=192 single pass
    mfma_gemm<0, 1, 192, 32, 2, 1><<<dim3(625, 1), blk, 0, stream>>>(featH, featL, N_NODES, 32,
        wb + WOFF_WIN, b_in, nullptr, nullptr, nullptr, nullptr, hH, hL, 192);

    for (int l = 0; l < 3; ++l) {
        const unsigned short* wq = wb + WOFF_QKV + l * 110592;
        // fused qkv, A-stationary BM=64: q -> qB, k/v -> kvB interleaved (single-term A)
        mfma_gemm_astat<0, 0, 96, 6, 1, 6, 1, 1><<<625, blk, 0, stream>>>(hH, hH, N_NODES,
            wq, nullptr, qB, kvB, 0);
        attn_kernel<<<10000, blk, 0, stream>>>(qB, kvB, ea, We + l * 768, csr2, rowp, msgH);
        // wo + residual + LN: DUAL resid (hH+hL) and DUAL output (htH+htL); msg single-term
        mfma_gemm<2, 1, 192, 64, 1, 1><<<dim3(625, 1), blk, 0, stream>>>(msgH, msgH, N_NODES, 192,
            wb + WOFF_WO + l * 36864, bo + l * 192, hH, hL, ln1g + l * 192, ln1b + l * 192,
            htH, htL, 192);
        // ff1: relu; A single-term (htH hi only — branch input, safe), output ffH single
        mfma_gemm_astat<1, 0, 96, 4, 1, 6, 0, 1><<<625, blk, 0, stream>>>(htH, htH, N_NODES,
            wb + WOFF_WF1 + l * 73728, bf1 + l * 384, ffH, nullptr, 384);
        // ff2 + residual + LN: DUAL resid (htH+htL) and DUAL output (hH+hL); ff single-term
        mfma_gemm<2, 1, 192, 64, 1, 1><<<dim3(625, 1), blk, 0, stream>>>(ffH, ffH, N_NODES, 384,
            wb + WOFF_WF2 + l * 73728, bf2 + l * 192, htH, htL, ln2g + l * 192, ln2b + l * 192,
            hH, hL, 192);
    }

    // edge head pre-projections, A-stationary BM=64, single-term A (hH): -> hsdB [N,384]
    mfma_gemm_astat<0, 0, 96, 4, 1, 6, 0, 1><<<625, blk, 0, stream>>>(hH, hH, N_NODES,
        wb + WOFF_HSD, nullptr, hsdB, nullptr, 384);
    edge_head_kernel<<<3125, blk, 0, stream>>>(hsdB, ea, src, dst,
        We1 + 384 * 192, be1, wb + WOFF_WE2, be2, We3, be3, (float*)d_out);
}